// Round 1
// baseline (1127.399 us; speedup 1.0000x reference)
//
#include <hip/hip_runtime.h>
#include <stdint.h>

#define N_NODES 100000
#define N_EDGES 1600000
#define EAD 7
#define H 64
#define LAT 32
#define NG 512
#define NC 6
#define NZ (N_NODES * LAT)

#define NB_SCAN 391            // ceil(N_NODES/256)
#define NPW1 10                // nodes per wave, conv1 (2500 blocks x 4 waves x 10 = 100000)
#define NPW2 10                // nodes per wave, conv2
#define HD_NPB 64

static_assert(N_NODES % (4 * NPW1) == 0, "conv1 grid exact");
static_assert(N_NODES % (4 * NPW2) == 0, "conv2 grid exact");
static_assert(N_EDGES % 256 == 0, "edge grid exact");

// ---------------- Threefry-2x32-20, key = (0, 42)  (jax.random.key(42)) ----
__device__ __forceinline__ void threefry2x32_42(uint32_t& x0, uint32_t& x1) {
    const uint32_t k0 = 0u, k1 = 42u;
    const uint32_t k2 = k0 ^ k1 ^ 0x1BD11BDAu;
    x0 += k0; x1 += k1;
#define TF_ROUND(r) { x0 += x1; x1 = (x1 << (r)) | (x1 >> (32 - (r))); x1 ^= x0; }
    TF_ROUND(13) TF_ROUND(15) TF_ROUND(26) TF_ROUND(6)
    x0 += k1; x1 += k2 + 1u;
    TF_ROUND(17) TF_ROUND(29) TF_ROUND(16) TF_ROUND(24)
    x0 += k2; x1 += k0 + 2u;
    TF_ROUND(13) TF_ROUND(15) TF_ROUND(26) TF_ROUND(6)
    x0 += k0; x1 += k1 + 3u;
    TF_ROUND(17) TF_ROUND(29) TF_ROUND(16) TF_ROUND(24)
    x0 += k1; x1 += k2 + 4u;
    TF_ROUND(13) TF_ROUND(15) TF_ROUND(26) TF_ROUND(6)
    x0 += k2; x1 += k0 + 5u;
#undef TF_ROUND
}

// XLA f32 ErfInv (Giles): matches jax.lax.erf_inv on f32
__device__ __forceinline__ float erfinv_f32(float x) {
    float w = -log1pf(-x * x);
    float p;
    if (w < 5.0f) {
        w = w - 2.5f;
        p = 2.81022636e-08f;
        p = fmaf(p, w, 3.43273939e-07f);
        p = fmaf(p, w, -3.5233877e-06f);
        p = fmaf(p, w, -4.39150654e-06f);
        p = fmaf(p, w, 0.00021858087f);
        p = fmaf(p, w, -0.00125372503f);
        p = fmaf(p, w, -0.00417768164f);
        p = fmaf(p, w, 0.246640727f);
        p = fmaf(p, w, 1.50140941f);
    } else {
        w = sqrtf(w) - 3.0f;
        p = -0.000200214257f;
        p = fmaf(p, w, 0.000100950558f);
        p = fmaf(p, w, 0.00134934322f);
        p = fmaf(p, w, -0.00367342844f);
        p = fmaf(p, w, 0.00573950773f);
        p = fmaf(p, w, -0.0076224613f);
        p = fmaf(p, w, 0.00943887047f);
        p = fmaf(p, w, 1.00167406f);
        p = fmaf(p, w, 2.83297682f);
    }
    return p * x;
}

// ---------------- CSR build: histogram of dst -------------------------------
__global__ void hist_k(const int* __restrict__ dst, int* __restrict__ deg) {
    int e = blockIdx.x * blockDim.x + threadIdx.x;
    if (e < N_EDGES) atomicAdd(&deg[dst[e]], 1);
}

// ---------------- CSR build: 3-pass exclusive scan over deg -----------------
__global__ void scan1_k(const int* __restrict__ deg, int* __restrict__ bsum) {
    __shared__ int sv[256];
    int t = threadIdx.x, i = blockIdx.x * 256 + t;
    sv[t] = (i < N_NODES) ? deg[i] : 0;
    __syncthreads();
    for (int o = 128; o > 0; o >>= 1) {
        if (t < o) sv[t] += sv[t + o];
        __syncthreads();
    }
    if (t == 0) bsum[blockIdx.x] = sv[0];
}

__global__ void scan2_k(int* __restrict__ bsum) {
    __shared__ int sv[512];
    int t = threadIdx.x;
    int v = (t < NB_SCAN) ? bsum[t] : 0;
    sv[t] = v;
    __syncthreads();
    for (int o = 1; o < 512; o <<= 1) {
        int a = (t >= o) ? sv[t - o] : 0;
        __syncthreads();
        sv[t] += a;
        __syncthreads();
    }
    if (t < NB_SCAN) bsum[t] = sv[t] - v;   // exclusive block offsets
}

__global__ void scan3_k(const int* __restrict__ deg, const int* __restrict__ bsum,
                        int* __restrict__ off, int* __restrict__ cur) {
    __shared__ int sv[256];
    int t = threadIdx.x, i = blockIdx.x * 256 + t;
    int v = (i < N_NODES) ? deg[i] : 0;
    sv[t] = v;
    __syncthreads();
    for (int o = 1; o < 256; o <<= 1) {
        int a = (t >= o) ? sv[t - o] : 0;
        __syncthreads();
        sv[t] += a;
        __syncthreads();
    }
    if (i < N_NODES) {
        int s = bsum[blockIdx.x] + sv[t] - v;
        off[i] = s;
        cur[i] = s;   // cursor; after scatter_k, cur[i] == segment end
    }
}

// ---------------- CSR build: scatter edges into dst-sorted order ------------
// Also precomputes conv1 message m1 = relu(x[src] + ea@We1 + be1) while ea is
// still read coalesced (edge-major).
__global__ void scatter_k(const float* __restrict__ x, const int* __restrict__ src,
                          const int* __restrict__ dst, const float* __restrict__ ea,
                          const float* __restrict__ We1, const float* __restrict__ be1,
                          int* __restrict__ cur, int2* __restrict__ rec8,
                          float* __restrict__ m1s) {
    int e = blockIdx.x * blockDim.x + threadIdx.x;
    if (e >= N_EDGES) return;
    int s = src[e], d = dst[e];
    const float* ep = ea + (size_t)e * EAD;
    float p = be1[0];
#pragma unroll
    for (int k = 0; k < EAD; k++) p = fmaf(ep[k], We1[k], p);
    float m = x[s] + p;
    m = m > 0.0f ? m : 0.0f;
    int pos = atomicAdd(&cur[d], 1);
    rec8[pos] = make_int2(s, e);
    m1s[pos] = m;
}

// ---------------- conv1: segmented sum of m1 + fused MLP 1->64->64 ----------
__global__ void conv1_fused(const float* __restrict__ x, const float* __restrict__ m1s,
                            const int* __restrict__ off, const int* __restrict__ cur,
                            const float* __restrict__ W11, const float* __restrict__ b11,
                            const float* __restrict__ W12, const float* __restrict__ b12,
                            const float* __restrict__ eps1, float* __restrict__ hA) {
    __shared__ float sW12[H * H];
    __shared__ float stg[4][H];
    int tid = threadIdx.x;
    for (int i = tid; i < H * H; i += 256) sW12[i] = W12[i];
    int w = tid >> 6, lane = tid & 63;
    float rW11 = W11[lane], rb11 = b11[lane], rb12 = b12[lane], er = eps1[0];
    __syncthreads();
    int n0 = (blockIdx.x * 4 + w) * NPW1;
    for (int ni = 0; ni < NPW1; ni++) {
        int n = n0 + ni;
        int g0 = off[n], g1 = cur[n];
        float agg = 0.0f;
        for (int j = g0 + lane; j < g1; j += 64) agg += m1s[j];
#pragma unroll
        for (int o = 32; o > 0; o >>= 1) agg += __shfl_xor(agg, o, 64);
        float xv = x[n];
        float h1 = fmaf(er, xv, xv) + agg;
        float t = fmaf(h1, rW11, rb11);
        t = t > 0.0f ? t : 0.0f;
        stg[w][lane] = t;                  // intra-wave staging (lockstep, no barrier)
        float acc = rb12;
#pragma unroll
        for (int j = 0; j < H; j++) acc = fmaf(stg[w][j], sW12[j * H + lane], acc);
        hA[(size_t)n * H + lane] = acc > 0.0f ? acc : 0.0f;
    }
}

// ---------------- conv2: windowed segmented gather + fused MLP 64->64->64 ---
// Per wave: nodes are contiguous, so their sorted edges form one contiguous
// range. Stage 64 edges {ea[7], src} at a time into LDS (per-lane parallel
// loads), then consume via broadcast reads; h-row gathers use a scalar base
// (readfirstlane) and are issued 4-deep for latency hiding. No atomics.
__global__ void conv2_fused(const float* __restrict__ hin, const int2* __restrict__ rec8,
                            const float* __restrict__ ea,
                            const int* __restrict__ off, const int* __restrict__ cur,
                            const float* __restrict__ We2, const float* __restrict__ be2,
                            const float* __restrict__ W21, const float* __restrict__ b21,
                            const float* __restrict__ W22, const float* __restrict__ b22,
                            const float* __restrict__ eps2, float* __restrict__ hB) {
    __shared__ float sW21[H * H], sW22[H * H];
    __shared__ float4 srec[4][64][2];
    __shared__ float stg[4][H];
    int tid = threadIdx.x;
    for (int i = tid; i < H * H; i += 256) { sW21[i] = W21[i]; sW22[i] = W22[i]; }
    int w = tid >> 6, lane = tid & 63;
    float rW[EAD];
#pragma unroll
    for (int k = 0; k < EAD; k++) rW[k] = We2[k * H + lane];
    float rbe2 = be2[lane], rb21 = b21[lane], rb22 = b22[lane], er = eps2[0];
    __syncthreads();

    int n0 = (blockIdx.x * 4 + w) * NPW2;
    int eend = cur[n0 + NPW2 - 1];
    int sbase = -(1 << 30);

    auto restage = [&](int g) {
        sbase = g;
        int cnt = eend - g; cnt = cnt > 64 ? 64 : cnt;
        float a0 = 0, a1 = 0, a2 = 0, a3 = 0, a4 = 0, a5 = 0, a6 = 0;
        int s = 0;
        if (lane < cnt) {
            int2 r = rec8[g + lane];
            s = r.x;
            const float* ep = ea + (size_t)r.y * EAD;
            a0 = ep[0]; a1 = ep[1]; a2 = ep[2]; a3 = ep[3];
            a4 = ep[4]; a5 = ep[5]; a6 = ep[6];
        }
        srec[w][lane][0] = make_float4(a0, a1, a2, a3);
        srec[w][lane][1] = make_float4(a4, a5, a6, __int_as_float(s));
    };

    for (int ni = 0; ni < NPW2; ni++) {
        int n = n0 + ni;
        int g = off[n], gend = cur[n];
        float acc = 0.0f;
        while (g + 4 <= gend) {
            if (g + 4 > sbase + 64) restage(g);
            int b = g - sbase;
            float4 A0 = srec[w][b + 0][0], B0 = srec[w][b + 0][1];
            float4 A1 = srec[w][b + 1][0], B1 = srec[w][b + 1][1];
            float4 A2 = srec[w][b + 2][0], B2 = srec[w][b + 2][1];
            float4 A3 = srec[w][b + 3][0], B3 = srec[w][b + 3][1];
            int s0 = __builtin_amdgcn_readfirstlane(__float_as_int(B0.w));
            int s1 = __builtin_amdgcn_readfirstlane(__float_as_int(B1.w));
            int s2 = __builtin_amdgcn_readfirstlane(__float_as_int(B2.w));
            int s3 = __builtin_amdgcn_readfirstlane(__float_as_int(B3.w));
            float hv0 = hin[(size_t)s0 * H + lane];
            float hv1 = hin[(size_t)s1 * H + lane];
            float hv2 = hin[(size_t)s2 * H + lane];
            float hv3 = hin[(size_t)s3 * H + lane];
            float p0 = rbe2, p1 = rbe2, p2 = rbe2, p3 = rbe2;
            p0 = fmaf(A0.x, rW[0], p0); p0 = fmaf(A0.y, rW[1], p0);
            p0 = fmaf(A0.z, rW[2], p0); p0 = fmaf(A0.w, rW[3], p0);
            p0 = fmaf(B0.x, rW[4], p0); p0 = fmaf(B0.y, rW[5], p0);
            p0 = fmaf(B0.z, rW[6], p0);
            p1 = fmaf(A1.x, rW[0], p1); p1 = fmaf(A1.y, rW[1], p1);
            p1 = fmaf(A1.z, rW[2], p1); p1 = fmaf(A1.w, rW[3], p1);
            p1 = fmaf(B1.x, rW[4], p1); p1 = fmaf(B1.y, rW[5], p1);
            p1 = fmaf(B1.z, rW[6], p1);
            p2 = fmaf(A2.x, rW[0], p2); p2 = fmaf(A2.y, rW[1], p2);
            p2 = fmaf(A2.z, rW[2], p2); p2 = fmaf(A2.w, rW[3], p2);
            p2 = fmaf(B2.x, rW[4], p2); p2 = fmaf(B2.y, rW[5], p2);
            p2 = fmaf(B2.z, rW[6], p2);
            p3 = fmaf(A3.x, rW[0], p3); p3 = fmaf(A3.y, rW[1], p3);
            p3 = fmaf(A3.z, rW[2], p3); p3 = fmaf(A3.w, rW[3], p3);
            p3 = fmaf(B3.x, rW[4], p3); p3 = fmaf(B3.y, rW[5], p3);
            p3 = fmaf(B3.z, rW[6], p3);
            acc += fmaxf(hv0 + p0, 0.0f);
            acc += fmaxf(hv1 + p1, 0.0f);
            acc += fmaxf(hv2 + p2, 0.0f);
            acc += fmaxf(hv3 + p3, 0.0f);
            g += 4;
        }
        while (g < gend) {
            if (g >= sbase + 64) restage(g);
            int b = g - sbase;
            float4 A = srec[w][b][0], B = srec[w][b][1];
            int s = __builtin_amdgcn_readfirstlane(__float_as_int(B.w));
            float hv = hin[(size_t)s * H + lane];
            float p = rbe2;
            p = fmaf(A.x, rW[0], p); p = fmaf(A.y, rW[1], p);
            p = fmaf(A.z, rW[2], p); p = fmaf(A.w, rW[3], p);
            p = fmaf(B.x, rW[4], p); p = fmaf(B.y, rW[5], p);
            p = fmaf(B.z, rW[6], p);
            acc += fmaxf(hv + p, 0.0f);
            g++;
        }
        // fused 2-layer MLP (wave-synchronous LDS staging)
        float hself = hin[(size_t)n * H + lane];
        float h2 = fmaf(er, hself, hself) + acc;
        stg[w][lane] = h2;
        float t = rb21;
#pragma unroll
        for (int j = 0; j < H; j++) t = fmaf(stg[w][j], sW21[j * H + lane], t);
        t = t > 0.0f ? t : 0.0f;
        stg[w][lane] = t;
        float o2 = rb22;
#pragma unroll
        for (int j = 0; j < H; j++) o2 = fmaf(stg[w][j], sW22[j * H + lane], o2);
        hB[(size_t)n * H + lane] = o2 > 0.0f ? o2 : 0.0f;
    }
}

// ---------------- heads: mu/logvar GEMVs + threefry noise + z, direct d_out -
__global__ void heads_mlz(const float* __restrict__ hB,
                          const float* __restrict__ Wmu, const float* __restrict__ bmu,
                          const float* __restrict__ Wlv, const float* __restrict__ blv,
                          float* __restrict__ out) {
    __shared__ float sWmu[H * LAT], sWlv[H * LAT];
    __shared__ float sh[8][H];
    int tid = threadIdx.x;
    for (int i = tid; i < H * LAT; i += 256) { sWmu[i] = Wmu[i]; sWlv[i] = Wlv[i]; }
    int sub = tid >> 5, lane = tid & 31;
    float bbmu = bmu[lane], bblv = blv[lane];
    __syncthreads();
    for (int it = 0; it < HD_NPB / 8; it++) {
        int base = blockIdx.x * HD_NPB + it * 8;
        if (base >= N_NODES) break;
        for (int i = tid; i < 8 * H; i += 256) {
            int nn = base + (i >> 6);
            if (nn < N_NODES) sh[i >> 6][i & 63] = hB[(size_t)nn * H + (i & 63)];
        }
        __syncthreads();
        int n = base + sub;
        if (n < N_NODES) {
            float mu = bbmu, lv = bblv;
#pragma unroll
            for (int j = 0; j < H; j++) {
                float hv = sh[sub][j];
                mu = fmaf(hv, sWmu[j * LAT + lane], mu);
                lv = fmaf(hv, sWlv[j * LAT + lane], lv);
            }
            int i = n * LAT + lane;
            uint32_t x0 = 0u, x1 = (uint32_t)i;
            threefry2x32_42(x0, x1);
            uint32_t bits = x0 ^ x1;
            float f = __uint_as_float((bits >> 9) | 0x3F800000u) - 1.0f;
            const float lo = -0.99999994f;
            float u = fmaxf(lo, fmaf(f, 2.0f, lo));
            float noise = 1.41421356237309515f * erfinv_f32(u);
            float z = fmaf(noise, expf(0.5f * lv), mu);
            out[i] = z;
            out[NZ + i] = mu;
            out[2 * NZ + i] = lv;
        }
        __syncthreads();
    }
}

// ---------------- pool + logits: float4 gathers of z in d_out; batch SORTED -
__global__ void pool_logits_k(const float4* __restrict__ z4, const int* __restrict__ batch,
                              const float* __restrict__ Wc, const float* __restrict__ bc,
                              float* __restrict__ out) {
    int g = blockIdx.x;
    int tid = threadIdx.x;
    int sub = tid >> 3, slot = tid & 7;
    __shared__ float4 acc4[32][8];
    __shared__ float emb[LAT];
    int lo = 0, hi = N_NODES;
    while (lo < hi) { int mid = (lo + hi) >> 1; if (batch[mid] < g) lo = mid + 1; else hi = mid; }
    int start = lo;
    hi = N_NODES;
    while (lo < hi) { int mid = (lo + hi) >> 1; if (batch[mid] < g + 1) lo = mid + 1; else hi = mid; }
    int end = lo;
    float4 a = make_float4(0.f, 0.f, 0.f, 0.f);
    for (int n = start + sub; n < end; n += 32) {
        float4 v = z4[(size_t)n * (LAT / 4) + slot];
        a.x += v.x; a.y += v.y; a.z += v.z; a.w += v.w;
    }
    acc4[sub][slot] = a;
    __syncthreads();
    if (tid < 8) {
        float4 s4 = acc4[0][tid];
        for (int k = 1; k < 32; k++) {
            s4.x += acc4[k][tid].x; s4.y += acc4[k][tid].y;
            s4.z += acc4[k][tid].z; s4.w += acc4[k][tid].w;
        }
        float invc = 1.0f / fmaxf((float)(end - start), 1.0f);
        emb[tid * 4 + 0] = s4.x * invc; emb[tid * 4 + 1] = s4.y * invc;
        emb[tid * 4 + 2] = s4.z * invc; emb[tid * 4 + 3] = s4.w * invc;
    }
    __syncthreads();
    if (tid < NC) {
        float r = bc[tid];
#pragma unroll
        for (int l = 0; l < LAT; l++) r = fmaf(emb[l], Wc[l * NC + tid], r);
        out[g * NC + tid] = r;
    }
}

extern "C" void kernel_launch(void* const* d_in, const int* in_sizes, int n_in,
                              void* d_out, int out_size, void* d_ws, size_t ws_size,
                              hipStream_t stream) {
    const float* x     = (const float*)d_in[0];
    const int*   ei    = (const int*)d_in[1];
    const float* ea    = (const float*)d_in[2];
    const int*   batch = (const int*)d_in[3];
    const float* We1   = (const float*)d_in[4];
    const float* be1   = (const float*)d_in[5];
    const float* W11   = (const float*)d_in[6];
    const float* b11   = (const float*)d_in[7];
    const float* W12   = (const float*)d_in[8];
    const float* b12   = (const float*)d_in[9];
    const float* eps1  = (const float*)d_in[10];
    const float* We2   = (const float*)d_in[11];
    const float* be2   = (const float*)d_in[12];
    const float* W21   = (const float*)d_in[13];
    const float* b21   = (const float*)d_in[14];
    const float* W22   = (const float*)d_in[15];
    const float* b22   = (const float*)d_in[16];
    const float* eps2  = (const float*)d_in[17];
    const float* Wmu   = (const float*)d_in[18];
    const float* bmu   = (const float*)d_in[19];
    const float* Wlv   = (const float*)d_in[20];
    const float* blv   = (const float*)d_in[21];
    const float* Wc    = (const float*)d_in[22];
    const float* bc    = (const float*)d_in[23];

    // ws layout (bytes, 46.0 MB total < proven 51.6 MB budget):
    //   [deg N int][off N int][cur N int][bsum 512 int]          1.20 MB
    //   [rec8 E int2]                                           12.80 MB
    //   [m1s E float]                                            6.40 MB
    //   [hB  N*H float]                                         25.60 MB
    // hA (conv1 output) lives in d_out[0 .. N*H) — dead before heads_mlz
    // overwrites that range with z and mu. No f32 atomics anywhere.
    int*   deg  = (int*)d_ws;
    int*   off  = deg + N_NODES;
    int*   cur  = off + N_NODES;
    int*   bsum = cur + N_NODES;
    int2*  rec8 = (int2*)(bsum + 512);
    float* m1s  = (float*)(rec8 + N_EDGES);
    float* hB   = m1s + N_EDGES;
    float* hA   = (float*)d_out;
    float* outf = (float*)d_out;

    hipMemsetAsync(deg, 0, N_NODES * sizeof(int), stream);

    const int* src = ei;
    const int* dst = ei + N_EDGES;

    hist_k<<<N_EDGES / 256, 256, 0, stream>>>(dst, deg);
    scan1_k<<<NB_SCAN, 256, 0, stream>>>(deg, bsum);
    scan2_k<<<1, 512, 0, stream>>>(bsum);
    scan3_k<<<NB_SCAN, 256, 0, stream>>>(deg, bsum, off, cur);
    scatter_k<<<N_EDGES / 256, 256, 0, stream>>>(x, src, dst, ea, We1, be1, cur, rec8, m1s);
    conv1_fused<<<N_NODES / (4 * NPW1), 256, 0, stream>>>(
        x, m1s, off, cur, W11, b11, W12, b12, eps1, hA);
    conv2_fused<<<N_NODES / (4 * NPW2), 256, 0, stream>>>(
        hA, rec8, ea, off, cur, We2, be2, W21, b21, W22, b22, eps2, hB);
    heads_mlz<<<(N_NODES + HD_NPB - 1) / HD_NPB, 256, 0, stream>>>(
        hB, Wmu, bmu, Wlv, blv, outf);
    pool_logits_k<<<NG, 256, 0, stream>>>((const float4*)outf, batch, Wc, bc,
                                          outf + 3 * (size_t)NZ);
}

// Round 3
// 1015.333 us; speedup vs baseline: 1.1104x; 1.1104x over previous
//
#include <hip/hip_runtime.h>
#include <stdint.h>

#define N_NODES 100000
#define N_EDGES 1600000
#define EAD 7
#define H 64
#define LAT 32
#define NG 512
#define NC 6
#define NZ (N_NODES * LAT)

#define NB_SCAN 391            // ceil(N_NODES/256)
#define NPW1 10                // nodes per wave, conv1 (2500 blocks x 4 waves x 10 = 100000)
#define NPW2 10                // nodes per wave, conv2_agg
#define C2_NPB 32              // nodes per block, conv2_node
#define HD_NPB 64

static_assert(N_NODES % (4 * NPW1) == 0, "conv1 grid exact");
static_assert(N_NODES % (4 * NPW2) == 0, "conv2_agg grid exact");
static_assert(N_NODES % C2_NPB == 0, "conv2_node grid exact");
static_assert(N_EDGES % 256 == 0, "edge grid exact");

// ---------------- Threefry-2x32-20, key = (0, 42)  (jax.random.key(42)) ----
__device__ __forceinline__ void threefry2x32_42(uint32_t& x0, uint32_t& x1) {
    const uint32_t k0 = 0u, k1 = 42u;
    const uint32_t k2 = k0 ^ k1 ^ 0x1BD11BDAu;
    x0 += k0; x1 += k1;
#define TF_ROUND(r) { x0 += x1; x1 = (x1 << (r)) | (x1 >> (32 - (r))); x1 ^= x0; }
    TF_ROUND(13) TF_ROUND(15) TF_ROUND(26) TF_ROUND(6)
    x0 += k1; x1 += k2 + 1u;
    TF_ROUND(17) TF_ROUND(29) TF_ROUND(16) TF_ROUND(24)
    x0 += k2; x1 += k0 + 2u;
    TF_ROUND(13) TF_ROUND(15) TF_ROUND(26) TF_ROUND(6)
    x0 += k0; x1 += k1 + 3u;
    TF_ROUND(17) TF_ROUND(29) TF_ROUND(16) TF_ROUND(24)
    x0 += k1; x1 += k2 + 4u;
    TF_ROUND(13) TF_ROUND(15) TF_ROUND(26) TF_ROUND(6)
    x0 += k2; x1 += k0 + 5u;
#undef TF_ROUND
}

// XLA f32 ErfInv (Giles): matches jax.lax.erf_inv on f32
__device__ __forceinline__ float erfinv_f32(float x) {
    float w = -log1pf(-x * x);
    float p;
    if (w < 5.0f) {
        w = w - 2.5f;
        p = 2.81022636e-08f;
        p = fmaf(p, w, 3.43273939e-07f);
        p = fmaf(p, w, -3.5233877e-06f);
        p = fmaf(p, w, -4.39150654e-06f);
        p = fmaf(p, w, 0.00021858087f);
        p = fmaf(p, w, -0.00125372503f);
        p = fmaf(p, w, -0.00417768164f);
        p = fmaf(p, w, 0.246640727f);
        p = fmaf(p, w, 1.50140941f);
    } else {
        w = sqrtf(w) - 3.0f;
        p = -0.000200214257f;
        p = fmaf(p, w, 0.000100950558f);
        p = fmaf(p, w, 0.00134934322f);
        p = fmaf(p, w, -0.00367342844f);
        p = fmaf(p, w, 0.00573950773f);
        p = fmaf(p, w, -0.0076224613f);
        p = fmaf(p, w, 0.00943887047f);
        p = fmaf(p, w, 1.00167406f);
        p = fmaf(p, w, 2.83297682f);
    }
    return p * x;
}

// ---------------- CSR build: histogram of dst -------------------------------
__global__ void hist_k(const int* __restrict__ dst, int* __restrict__ deg) {
    int e = blockIdx.x * blockDim.x + threadIdx.x;
    if (e < N_EDGES) atomicAdd(&deg[dst[e]], 1);
}

// ---------------- CSR build: 3-pass exclusive scan over deg -----------------
__global__ void scan1_k(const int* __restrict__ deg, int* __restrict__ bsum) {
    __shared__ int sv[256];
    int t = threadIdx.x, i = blockIdx.x * 256 + t;
    sv[t] = (i < N_NODES) ? deg[i] : 0;
    __syncthreads();
    for (int o = 128; o > 0; o >>= 1) {
        if (t < o) sv[t] += sv[t + o];
        __syncthreads();
    }
    if (t == 0) bsum[blockIdx.x] = sv[0];
}

__global__ void scan2_k(int* __restrict__ bsum) {
    __shared__ int sv[512];
    int t = threadIdx.x;
    int v = (t < NB_SCAN) ? bsum[t] : 0;
    sv[t] = v;
    __syncthreads();
    for (int o = 1; o < 512; o <<= 1) {
        int a = (t >= o) ? sv[t - o] : 0;
        __syncthreads();
        sv[t] += a;
        __syncthreads();
    }
    if (t < NB_SCAN) bsum[t] = sv[t] - v;   // exclusive block offsets
}

__global__ void scan3_k(const int* __restrict__ deg, const int* __restrict__ bsum,
                        int* __restrict__ off, int* __restrict__ cur) {
    __shared__ int sv[256];
    int t = threadIdx.x, i = blockIdx.x * 256 + t;
    int v = (i < N_NODES) ? deg[i] : 0;
    sv[t] = v;
    __syncthreads();
    for (int o = 1; o < 256; o <<= 1) {
        int a = (t >= o) ? sv[t - o] : 0;
        __syncthreads();
        sv[t] += a;
        __syncthreads();
    }
    if (i < N_NODES) {
        int s = bsum[blockIdx.x] + sv[t] - v;
        off[i] = s;
        cur[i] = s;   // cursor; after scatter_k, cur[i] == segment end
    }
}

// ---------------- CSR build: scatter edges into dst-sorted order ------------
// Also precomputes conv1 message m1 = relu(x[src] + ea@We1 + be1) while ea is
// still read coalesced (edge-major).
__global__ void scatter_k(const float* __restrict__ x, const int* __restrict__ src,
                          const int* __restrict__ dst, const float* __restrict__ ea,
                          const float* __restrict__ We1, const float* __restrict__ be1,
                          int* __restrict__ cur, int2* __restrict__ rec8,
                          float* __restrict__ m1s) {
    int e = blockIdx.x * blockDim.x + threadIdx.x;
    if (e >= N_EDGES) return;
    int s = src[e], d = dst[e];
    const float* ep = ea + (size_t)e * EAD;
    float p = be1[0];
#pragma unroll
    for (int k = 0; k < EAD; k++) p = fmaf(ep[k], We1[k], p);
    float m = x[s] + p;
    m = m > 0.0f ? m : 0.0f;
    int pos = atomicAdd(&cur[d], 1);
    rec8[pos] = make_int2(s, e);
    m1s[pos] = m;
}

// ---------------- conv1: segmented sum of m1 + fused MLP 1->64->64 ----------
// hA lives in d_ws (cached): dword stores fine, and conv2's gathers hit L2/L3.
__global__ void conv1_fused(const float* __restrict__ x, const float* __restrict__ m1s,
                            const int* __restrict__ off, const int* __restrict__ cur,
                            const float* __restrict__ W11, const float* __restrict__ b11,
                            const float* __restrict__ W12, const float* __restrict__ b12,
                            const float* __restrict__ eps1, float* __restrict__ hA) {
    __shared__ float sW12[H * H];
    __shared__ float stg[4][H];
    int tid = threadIdx.x;
    for (int i = tid; i < H * H; i += 256) sW12[i] = W12[i];
    int w = tid >> 6, lane = tid & 63;
    float rW11 = W11[lane], rb11 = b11[lane], rb12 = b12[lane], er = eps1[0];
    __syncthreads();
    int n0 = (blockIdx.x * 4 + w) * NPW1;
    for (int ni = 0; ni < NPW1; ni++) {
        int n = n0 + ni;
        int g0 = off[n], g1 = cur[n];
        float agg = 0.0f;
        for (int j = g0 + lane; j < g1; j += 64) agg += m1s[j];
#pragma unroll
        for (int o = 32; o > 0; o >>= 1) agg += __shfl_xor(agg, o, 64);
        float xv = x[n];
        float h1 = fmaf(er, xv, xv) + agg;
        float t = fmaf(h1, rW11, rb11);
        t = t > 0.0f ? t : 0.0f;
        stg[w][lane] = t;                  // intra-wave staging (lockstep)
        float acc = rb12;
#pragma unroll
        for (int j = 0; j < H; j++) acc = fmaf(stg[w][j], sW12[j * H + lane], acc);
        hA[(size_t)n * H + lane] = acc > 0.0f ? acc : 0.0f;
    }
}

// ---------------- conv2 stage A: windowed segmented gather -> agg rows ------
// No weights in LDS (9 KB total) -> high occupancy for the latency-bound
// gather phase. Per-wave independent; no block barriers. Output rows written
// float4 to d_out staging (dense, wave-uniform row).
__global__ void conv2_agg(const float* __restrict__ hin, const int2* __restrict__ rec8,
                          const float* __restrict__ ea,
                          const int* __restrict__ off, const int* __restrict__ cur,
                          const float* __restrict__ We2, const float* __restrict__ be2,
                          float4* __restrict__ agg4) {
    __shared__ float4 srec[4][64][2];
    __shared__ float stg[4][H];
    int tid = threadIdx.x;
    int w = tid >> 6, lane = tid & 63;
    float rW[EAD];
#pragma unroll
    for (int k = 0; k < EAD; k++) rW[k] = We2[k * H + lane];
    float rbe2 = be2[lane];

    int n0 = (blockIdx.x * 4 + w) * NPW2;
    int eend = cur[n0 + NPW2 - 1];
    int sbase = -(1 << 30);

    auto restage = [&](int g) {
        sbase = g;
        int cnt = eend - g; cnt = cnt > 64 ? 64 : cnt;
        float a0 = 0, a1 = 0, a2 = 0, a3 = 0, a4 = 0, a5 = 0, a6 = 0;
        int s = 0;
        if (lane < cnt) {
            int2 r = rec8[g + lane];
            s = r.x;
            const float* ep = ea + (size_t)r.y * EAD;
            a0 = ep[0]; a1 = ep[1]; a2 = ep[2]; a3 = ep[3];
            a4 = ep[4]; a5 = ep[5]; a6 = ep[6];
        }
        srec[w][lane][0] = make_float4(a0, a1, a2, a3);
        srec[w][lane][1] = make_float4(a4, a5, a6, __int_as_float(s));
    };

    for (int ni = 0; ni < NPW2; ni++) {
        int n = n0 + ni;
        int g = off[n], gend = cur[n];
        float acc = 0.0f;
        while (g + 4 <= gend) {
            if (g + 4 > sbase + 64) restage(g);
            int b = g - sbase;
            float4 A0 = srec[w][b + 0][0], B0 = srec[w][b + 0][1];
            float4 A1 = srec[w][b + 1][0], B1 = srec[w][b + 1][1];
            float4 A2 = srec[w][b + 2][0], B2 = srec[w][b + 2][1];
            float4 A3 = srec[w][b + 3][0], B3 = srec[w][b + 3][1];
            int s0 = __builtin_amdgcn_readfirstlane(__float_as_int(B0.w));
            int s1 = __builtin_amdgcn_readfirstlane(__float_as_int(B1.w));
            int s2 = __builtin_amdgcn_readfirstlane(__float_as_int(B2.w));
            int s3 = __builtin_amdgcn_readfirstlane(__float_as_int(B3.w));
            float hv0 = hin[(size_t)s0 * H + lane];
            float hv1 = hin[(size_t)s1 * H + lane];
            float hv2 = hin[(size_t)s2 * H + lane];
            float hv3 = hin[(size_t)s3 * H + lane];
            float p0 = rbe2, p1 = rbe2, p2 = rbe2, p3 = rbe2;
            p0 = fmaf(A0.x, rW[0], p0); p0 = fmaf(A0.y, rW[1], p0);
            p0 = fmaf(A0.z, rW[2], p0); p0 = fmaf(A0.w, rW[3], p0);
            p0 = fmaf(B0.x, rW[4], p0); p0 = fmaf(B0.y, rW[5], p0);
            p0 = fmaf(B0.z, rW[6], p0);
            p1 = fmaf(A1.x, rW[0], p1); p1 = fmaf(A1.y, rW[1], p1);
            p1 = fmaf(A1.z, rW[2], p1); p1 = fmaf(A1.w, rW[3], p1);
            p1 = fmaf(B1.x, rW[4], p1); p1 = fmaf(B1.y, rW[5], p1);
            p1 = fmaf(B1.z, rW[6], p1);
            p2 = fmaf(A2.x, rW[0], p2); p2 = fmaf(A2.y, rW[1], p2);
            p2 = fmaf(A2.z, rW[2], p2); p2 = fmaf(A2.w, rW[3], p2);
            p2 = fmaf(B2.x, rW[4], p2); p2 = fmaf(B2.y, rW[5], p2);
            p2 = fmaf(B2.z, rW[6], p2);
            p3 = fmaf(A3.x, rW[0], p3); p3 = fmaf(A3.y, rW[1], p3);
            p3 = fmaf(A3.z, rW[2], p3); p3 = fmaf(A3.w, rW[3], p3);
            p3 = fmaf(B3.x, rW[4], p3); p3 = fmaf(B3.y, rW[5], p3);
            p3 = fmaf(B3.z, rW[6], p3);
            acc += fmaxf(hv0 + p0, 0.0f);
            acc += fmaxf(hv1 + p1, 0.0f);
            acc += fmaxf(hv2 + p2, 0.0f);
            acc += fmaxf(hv3 + p3, 0.0f);
            g += 4;
        }
        while (g < gend) {
            if (g >= sbase + 64) restage(g);
            int b = g - sbase;
            float4 A = srec[w][b][0], B = srec[w][b][1];
            int s = __builtin_amdgcn_readfirstlane(__float_as_int(B.w));
            float hv = hin[(size_t)s * H + lane];
            float p = rbe2;
            p = fmaf(A.x, rW[0], p); p = fmaf(A.y, rW[1], p);
            p = fmaf(A.z, rW[2], p); p = fmaf(A.w, rW[3], p);
            p = fmaf(B.x, rW[4], p); p = fmaf(B.y, rW[5], p);
            p = fmaf(B.z, rW[6], p);
            acc += fmaxf(hv + p, 0.0f);
            g++;
        }
        // wave-synchronous float4 row store to d_out staging
        stg[w][lane] = acc;
        if (lane < 16) {
            float4 v = make_float4(stg[w][lane * 4 + 0], stg[w][lane * 4 + 1],
                                   stg[w][lane * 4 + 2], stg[w][lane * 4 + 3]);
            agg4[(size_t)n * 16 + lane] = v;
        }
    }
}

// ---------------- conv2 stage B: per-node MLP 64->64->64, in-place on hA ----
__global__ void conv2_node(float* __restrict__ hA, const float* __restrict__ agg2,
                           const float* __restrict__ W21, const float* __restrict__ b21,
                           const float* __restrict__ W22, const float* __restrict__ b22,
                           const float* __restrict__ eps2) {
    __shared__ float sW21[H * H], sW22[H * H];
    __shared__ float sh2[4][H], st[4][H];
    int tid = threadIdx.x;
    for (int i = tid; i < H * H; i += 256) { sW21[i] = W21[i]; sW22[i] = W22[i]; }
    int sub = tid >> 6, lane = tid & 63;
    float e = eps2[0];
    float bb21 = b21[lane], bb22 = b22[lane];
    __syncthreads();
#pragma unroll
    for (int it = 0; it < C2_NPB / 4; it++) {
        int n = blockIdx.x * C2_NPB + it * 4 + sub;
        float hv = hA[(size_t)n * H + lane];
        sh2[sub][lane] = fmaf(e, hv, hv) + agg2[(size_t)n * H + lane];
        __syncthreads();
        float acc = bb21;
#pragma unroll
        for (int j = 0; j < H; j++) acc = fmaf(sh2[sub][j], sW21[j * H + lane], acc);
        st[sub][lane] = acc > 0.0f ? acc : 0.0f;
        __syncthreads();
        acc = bb22;
#pragma unroll
        for (int j = 0; j < H; j++) acc = fmaf(st[sub][j], sW22[j * H + lane], acc);
        hA[(size_t)n * H + lane] = acc > 0.0f ? acc : 0.0f;
        __syncthreads();
    }
}

// ---------------- heads: mu/lv GEMVs + threefry z; float4 coop -> d_out -----
// Reads hA from ws (cached). Stages 8-node tiles of z/mu/lv in LDS, then
// cooperative float4 stores to final d_out offsets (only dense float4 ever
// touches d_out). Also drops a dword copy of z into ws for pool's gathers.
__global__ void heads_fz(const float* __restrict__ hA,
                         const float* __restrict__ Wmu, const float* __restrict__ bmu,
                         const float* __restrict__ Wlv, const float* __restrict__ blv,
                         float4* __restrict__ out4, float* __restrict__ zws) {
    __shared__ float sWmu[H * LAT], sWlv[H * LAT];
    __shared__ float sh[8][H];
    __shared__ float sz[8][LAT], smu[8][LAT], slv[8][LAT];
    int tid = threadIdx.x;
    for (int i = tid; i < H * LAT; i += 256) { sWmu[i] = Wmu[i]; sWlv[i] = Wlv[i]; }
    int sub = tid >> 5, lane = tid & 31;
    float bbmu = bmu[lane], bblv = blv[lane];
    __syncthreads();
    for (int it = 0; it < HD_NPB / 8; it++) {
        int base = blockIdx.x * HD_NPB + it * 8;
        if (base >= N_NODES) break;
        for (int i = tid; i < 8 * H; i += 256) {
            int nn = base + (i >> 6);
            if (nn < N_NODES) sh[i >> 6][i & 63] = hA[(size_t)nn * H + (i & 63)];
        }
        __syncthreads();
        int n = base + sub;
        if (n < N_NODES) {
            float mu = bbmu, lv = bblv;
#pragma unroll
            for (int j = 0; j < H; j++) {
                float hv = sh[sub][j];
                mu = fmaf(hv, sWmu[j * LAT + lane], mu);
                lv = fmaf(hv, sWlv[j * LAT + lane], lv);
            }
            int i = n * LAT + lane;
            uint32_t x0 = 0u, x1 = (uint32_t)i;
            threefry2x32_42(x0, x1);
            uint32_t bits = x0 ^ x1;
            float f = __uint_as_float((bits >> 9) | 0x3F800000u) - 1.0f;
            const float lo = -0.99999994f;
            float u = fmaxf(lo, fmaf(f, 2.0f, lo));
            float noise = 1.41421356237309515f * erfinv_f32(u);
            float z = fmaf(noise, expf(0.5f * lv), mu);
            sz[sub][lane] = z; smu[sub][lane] = mu; slv[sub][lane] = lv;
            zws[i] = z;
        }
        __syncthreads();
        if (tid < 192) {
            int grp = tid >> 6;                 // 0=z, 1=mu, 2=lv
            int q = tid & 63;                   // float4 index within tile
            int nl = q >> 3, f4 = q & 7;
            if (base + nl < N_NODES) {
                const float* s = (grp == 0) ? &sz[0][0] : (grp == 1) ? &smu[0][0] : &slv[0][0];
                float4 v = ((const float4*)s)[q];
                out4[(size_t)grp * (NZ / 4) + (size_t)(base + nl) * 8 + f4] = v;
            }
        }
        __syncthreads();
    }
}

// ---------------- pool + logits: float4 gathers of z from ws; batch SORTED --
__global__ void pool_logits_k(const float4* __restrict__ z4, const int* __restrict__ batch,
                              const float* __restrict__ Wc, const float* __restrict__ bc,
                              float* __restrict__ out) {
    int g = blockIdx.x;
    int tid = threadIdx.x;
    int sub = tid >> 3, slot = tid & 7;
    __shared__ float4 acc4[32][8];
    __shared__ float emb[LAT];
    int lo = 0, hi = N_NODES;
    while (lo < hi) { int mid = (lo + hi) >> 1; if (batch[mid] < g) lo = mid + 1; else hi = mid; }
    int start = lo;
    hi = N_NODES;
    while (lo < hi) { int mid = (lo + hi) >> 1; if (batch[mid] < g + 1) lo = mid + 1; else hi = mid; }
    int end = lo;
    float4 a = make_float4(0.f, 0.f, 0.f, 0.f);
    for (int n = start + sub; n < end; n += 32) {
        float4 v = z4[(size_t)n * (LAT / 4) + slot];
        a.x += v.x; a.y += v.y; a.z += v.z; a.w += v.w;
    }
    acc4[sub][slot] = a;
    __syncthreads();
    if (tid < 8) {
        float4 s4 = acc4[0][tid];
        for (int k = 1; k < 32; k++) {
            s4.x += acc4[k][tid].x; s4.y += acc4[k][tid].y;
            s4.z += acc4[k][tid].z; s4.w += acc4[k][tid].w;
        }
        float invc = 1.0f / fmaxf((float)(end - start), 1.0f);
        emb[tid * 4 + 0] = s4.x * invc; emb[tid * 4 + 1] = s4.y * invc;
        emb[tid * 4 + 2] = s4.z * invc; emb[tid * 4 + 3] = s4.w * invc;
    }
    __syncthreads();
    if (tid < NC) {
        float r = bc[tid];
#pragma unroll
        for (int l = 0; l < LAT; l++) r = fmaf(emb[l], Wc[l * NC + tid], r);
        out[g * NC + tid] = r;
    }
}

extern "C" void kernel_launch(void* const* d_in, const int* in_sizes, int n_in,
                              void* d_out, int out_size, void* d_ws, size_t ws_size,
                              hipStream_t stream) {
    const float* x     = (const float*)d_in[0];
    const int*   ei    = (const int*)d_in[1];
    const float* ea    = (const float*)d_in[2];
    const int*   batch = (const int*)d_in[3];
    const float* We1   = (const float*)d_in[4];
    const float* be1   = (const float*)d_in[5];
    const float* W11   = (const float*)d_in[6];
    const float* b11   = (const float*)d_in[7];
    const float* W12   = (const float*)d_in[8];
    const float* b12   = (const float*)d_in[9];
    const float* eps1  = (const float*)d_in[10];
    const float* We2   = (const float*)d_in[11];
    const float* be2   = (const float*)d_in[12];
    const float* W21   = (const float*)d_in[13];
    const float* b21   = (const float*)d_in[14];
    const float* W22   = (const float*)d_in[15];
    const float* b22   = (const float*)d_in[16];
    const float* eps2  = (const float*)d_in[17];
    const float* Wmu   = (const float*)d_in[18];
    const float* bmu   = (const float*)d_in[19];
    const float* Wlv   = (const float*)d_in[20];
    const float* blv   = (const float*)d_in[21];
    const float* Wc    = (const float*)d_in[22];
    const float* bc    = (const float*)d_in[23];

    // ws layout (46.0 MB < proven 51.6 MB budget). ALL scalar/gather traffic
    // stays in ws; d_out only ever receives dense float4 stores.
    //   [deg N][off N][cur N][bsum 512]      ints   1.20 MB
    //   [rec8 E int2]                               12.80 MB  (dead after conv2_agg -> zws)
    //   [m1s E float]                                6.40 MB
    //   [hA  N*H float]                             25.60 MB  (conv1 out, conv2 in-place)
    // d_out staging: agg2 rows [0..25.6MB) via float4, dead after conv2_node,
    // then overwritten by heads' final z/mu/lv float4 stores.
    int*   deg  = (int*)d_ws;
    int*   off  = deg + N_NODES;
    int*   cur  = off + N_NODES;
    int*   bsum = cur + N_NODES;
    int2*  rec8 = (int2*)(bsum + 512);
    float* m1s  = (float*)(rec8 + N_EDGES);
    float* hA   = m1s + N_EDGES;
    float* zws  = (float*)rec8;             // reuse: rec8 dead after conv2_agg
    float* agg2 = (float*)d_out;            // staging rows in d_out
    float* outf = (float*)d_out;

    hipMemsetAsync(deg, 0, N_NODES * sizeof(int), stream);

    const int* src = ei;
    const int* dst = ei + N_EDGES;

    hist_k<<<N_EDGES / 256, 256, 0, stream>>>(dst, deg);
    scan1_k<<<NB_SCAN, 256, 0, stream>>>(deg, bsum);
    scan2_k<<<1, 512, 0, stream>>>(bsum);
    scan3_k<<<NB_SCAN, 256, 0, stream>>>(deg, bsum, off, cur);
    scatter_k<<<N_EDGES / 256, 256, 0, stream>>>(x, src, dst, ea, We1, be1, cur, rec8, m1s);
    conv1_fused<<<N_NODES / (4 * NPW1), 256, 0, stream>>>(
        x, m1s, off, cur, W11, b11, W12, b12, eps1, hA);
    conv2_agg<<<N_NODES / (4 * NPW2), 256, 0, stream>>>(
        hA, rec8, ea, off, cur, We2, be2, (float4*)agg2);
    conv2_node<<<N_NODES / C2_NPB, 256, 0, stream>>>(hA, agg2, W21, b21, W22, b22, eps2);
    heads_fz<<<(N_NODES + HD_NPB - 1) / HD_NPB, 256, 0, stream>>>(
        hA, Wmu, bmu, Wlv, blv, (float4*)outf, zws);
    pool_logits_k<<<NG, 256, 0, stream>>>((const float4*)zws, batch, Wc, bc,
                                          outf + 3 * (size_t)NZ);
}

// Round 4
// 864.866 us; speedup vs baseline: 1.3036x; 1.1740x over previous
//
#include <hip/hip_runtime.h>
#include <stdint.h>

#define N_NODES 100000
#define N_EDGES 1600000
#define EAD 7
#define H 64
#define LAT 32
#define NG 512
#define NC 6
#define NZ (N_NODES * LAT)

#define NB_SCAN 391            // ceil(N_NODES/256)
#define NPW1 4                 // nodes per wave, conv1 (6250 blocks)
#define NPW2 2                 // nodes per wave, conv2_agg (12500 blocks)
#define C2_NPB 32              // nodes per block, conv2_node
#define HD_NPB 8               // nodes per block, heads (12500 blocks, no serial loop)

static_assert(N_NODES % (4 * NPW1) == 0, "conv1 grid exact");
static_assert(N_NODES % (4 * NPW2) == 0, "conv2_agg grid exact");
static_assert(N_NODES % C2_NPB == 0, "conv2_node grid exact");
static_assert(N_NODES % HD_NPB == 0, "heads grid exact");
static_assert(N_EDGES % 256 == 0, "edge grid exact");

// ---------------- Threefry-2x32-20, key = (0, 42)  (jax.random.key(42)) ----
__device__ __forceinline__ void threefry2x32_42(uint32_t& x0, uint32_t& x1) {
    const uint32_t k0 = 0u, k1 = 42u;
    const uint32_t k2 = k0 ^ k1 ^ 0x1BD11BDAu;
    x0 += k0; x1 += k1;
#define TF_ROUND(r) { x0 += x1; x1 = (x1 << (r)) | (x1 >> (32 - (r))); x1 ^= x0; }
    TF_ROUND(13) TF_ROUND(15) TF_ROUND(26) TF_ROUND(6)
    x0 += k1; x1 += k2 + 1u;
    TF_ROUND(17) TF_ROUND(29) TF_ROUND(16) TF_ROUND(24)
    x0 += k2; x1 += k0 + 2u;
    TF_ROUND(13) TF_ROUND(15) TF_ROUND(26) TF_ROUND(6)
    x0 += k0; x1 += k1 + 3u;
    TF_ROUND(17) TF_ROUND(29) TF_ROUND(16) TF_ROUND(24)
    x0 += k1; x1 += k2 + 4u;
    TF_ROUND(13) TF_ROUND(15) TF_ROUND(26) TF_ROUND(6)
    x0 += k2; x1 += k0 + 5u;
#undef TF_ROUND
}

// XLA f32 ErfInv (Giles): matches jax.lax.erf_inv on f32
__device__ __forceinline__ float erfinv_f32(float x) {
    float w = -log1pf(-x * x);
    float p;
    if (w < 5.0f) {
        w = w - 2.5f;
        p = 2.81022636e-08f;
        p = fmaf(p, w, 3.43273939e-07f);
        p = fmaf(p, w, -3.5233877e-06f);
        p = fmaf(p, w, -4.39150654e-06f);
        p = fmaf(p, w, 0.00021858087f);
        p = fmaf(p, w, -0.00125372503f);
        p = fmaf(p, w, -0.00417768164f);
        p = fmaf(p, w, 0.246640727f);
        p = fmaf(p, w, 1.50140941f);
    } else {
        w = sqrtf(w) - 3.0f;
        p = -0.000200214257f;
        p = fmaf(p, w, 0.000100950558f);
        p = fmaf(p, w, 0.00134934322f);
        p = fmaf(p, w, -0.00367342844f);
        p = fmaf(p, w, 0.00573950773f);
        p = fmaf(p, w, -0.0076224613f);
        p = fmaf(p, w, 0.00943887047f);
        p = fmaf(p, w, 1.00167406f);
        p = fmaf(p, w, 2.83297682f);
    }
    return p * x;
}

// ---------------- CSR build: histogram of dst -------------------------------
__global__ void hist_k(const int* __restrict__ dst, int* __restrict__ deg) {
    int e = blockIdx.x * blockDim.x + threadIdx.x;
    if (e < N_EDGES) atomicAdd(&deg[dst[e]], 1);
}

// ---------------- CSR build: 3-pass exclusive scan over deg -----------------
__global__ void scan1_k(const int* __restrict__ deg, int* __restrict__ bsum) {
    __shared__ int sv[256];
    int t = threadIdx.x, i = blockIdx.x * 256 + t;
    sv[t] = (i < N_NODES) ? deg[i] : 0;
    __syncthreads();
    for (int o = 128; o > 0; o >>= 1) {
        if (t < o) sv[t] += sv[t + o];
        __syncthreads();
    }
    if (t == 0) bsum[blockIdx.x] = sv[0];
}

__global__ void scan2_k(int* __restrict__ bsum) {
    __shared__ int sv[512];
    int t = threadIdx.x;
    int v = (t < NB_SCAN) ? bsum[t] : 0;
    sv[t] = v;
    __syncthreads();
    for (int o = 1; o < 512; o <<= 1) {
        int a = (t >= o) ? sv[t - o] : 0;
        __syncthreads();
        sv[t] += a;
        __syncthreads();
    }
    if (t < NB_SCAN) bsum[t] = sv[t] - v;   // exclusive block offsets
}

__global__ void scan3_k(const int* __restrict__ deg, const int* __restrict__ bsum,
                        int* __restrict__ off, int* __restrict__ cur) {
    __shared__ int sv[256];
    int t = threadIdx.x, i = blockIdx.x * 256 + t;
    int v = (i < N_NODES) ? deg[i] : 0;
    sv[t] = v;
    __syncthreads();
    for (int o = 1; o < 256; o <<= 1) {
        int a = (t >= o) ? sv[t - o] : 0;
        __syncthreads();
        sv[t] += a;
        __syncthreads();
    }
    if (i < N_NODES) {
        int s = bsum[blockIdx.x] + sv[t] - v;
        off[i] = s;
        cur[i] = s;   // cursor; after scatter_k, cur[i] == segment end
    }
}

// ---------------- CSR build: scatter edges into dst-sorted order ------------
// Also precomputes conv1 message m1 = relu(x[src] + ea@We1 + be1) while ea is
// still read coalesced (edge-major).
__global__ void scatter_k(const float* __restrict__ x, const int* __restrict__ src,
                          const int* __restrict__ dst, const float* __restrict__ ea,
                          const float* __restrict__ We1, const float* __restrict__ be1,
                          int* __restrict__ cur, int2* __restrict__ rec8,
                          float* __restrict__ m1s) {
    int e = blockIdx.x * blockDim.x + threadIdx.x;
    if (e >= N_EDGES) return;
    int s = src[e], d = dst[e];
    const float* ep = ea + (size_t)e * EAD;
    float p = be1[0];
#pragma unroll
    for (int k = 0; k < EAD; k++) p = fmaf(ep[k], We1[k], p);
    float m = x[s] + p;
    m = m > 0.0f ? m : 0.0f;
    int pos = atomicAdd(&cur[d], 1);
    rec8[pos] = make_int2(s, e);
    m1s[pos] = m;
}

// ---------------- conv1: segmented sum of m1 + fused MLP 1->64->64 ----------
__global__ void conv1_fused(const float* __restrict__ x, const float* __restrict__ m1s,
                            const int* __restrict__ off, const int* __restrict__ cur,
                            const float* __restrict__ W11, const float* __restrict__ b11,
                            const float* __restrict__ W12, const float* __restrict__ b12,
                            const float* __restrict__ eps1, float* __restrict__ hA) {
    __shared__ float sW12[H * H];
    __shared__ float stg[4][H];
    int tid = threadIdx.x;
    for (int i = tid; i < H * H; i += 256) sW12[i] = W12[i];
    int w = tid >> 6, lane = tid & 63;
    float rW11 = W11[lane], rb11 = b11[lane], rb12 = b12[lane], er = eps1[0];
    __syncthreads();
    int n0 = (blockIdx.x * 4 + w) * NPW1;
#pragma unroll
    for (int ni = 0; ni < NPW1; ni++) {
        int n = n0 + ni;
        int g0 = off[n], g1 = cur[n];
        float agg = 0.0f;
        for (int j = g0 + lane; j < g1; j += 64) agg += m1s[j];
#pragma unroll
        for (int o = 32; o > 0; o >>= 1) agg += __shfl_xor(agg, o, 64);
        float xv = x[n];
        float h1 = fmaf(er, xv, xv) + agg;
        float t = fmaf(h1, rW11, rb11);
        t = t > 0.0f ? t : 0.0f;
        stg[w][lane] = t;                  // intra-wave staging (lockstep)
        float acc = rb12;
#pragma unroll
        for (int j = 0; j < H; j++) acc = fmaf(stg[w][j], sW12[j * H + lane], acc);
        hA[(size_t)n * H + lane] = acc > 0.0f ? acc : 0.0f;
    }
}

// ---------------- conv2 stage A: windowed segmented gather -> agg rows ------
// 2 nodes per wave -> 12500 blocks; 9 KB LDS -> wave-cap occupancy. Per-wave
// independent; no block barriers; no atomics.
__global__ void conv2_agg(const float* __restrict__ hin, const int2* __restrict__ rec8,
                          const float* __restrict__ ea,
                          const int* __restrict__ off, const int* __restrict__ cur,
                          const float* __restrict__ We2, const float* __restrict__ be2,
                          float4* __restrict__ agg4) {
    __shared__ float4 srec[4][64][2];
    __shared__ float stg[4][H];
    int tid = threadIdx.x;
    int w = tid >> 6, lane = tid & 63;
    float rW[EAD];
#pragma unroll
    for (int k = 0; k < EAD; k++) rW[k] = We2[k * H + lane];
    float rbe2 = be2[lane];

    int n0 = (blockIdx.x * 4 + w) * NPW2;
    int eend = cur[n0 + NPW2 - 1];
    int sbase = -(1 << 30);

    auto restage = [&](int g) {
        sbase = g;
        int cnt = eend - g; cnt = cnt > 64 ? 64 : cnt;
        float a0 = 0, a1 = 0, a2 = 0, a3 = 0, a4 = 0, a5 = 0, a6 = 0;
        int s = 0;
        if (lane < cnt) {
            int2 r = rec8[g + lane];
            s = r.x;
            const float* ep = ea + (size_t)r.y * EAD;
            a0 = ep[0]; a1 = ep[1]; a2 = ep[2]; a3 = ep[3];
            a4 = ep[4]; a5 = ep[5]; a6 = ep[6];
        }
        srec[w][lane][0] = make_float4(a0, a1, a2, a3);
        srec[w][lane][1] = make_float4(a4, a5, a6, __int_as_float(s));
    };

#pragma unroll
    for (int ni = 0; ni < NPW2; ni++) {
        int n = n0 + ni;
        int g = off[n], gend = cur[n];
        float acc = 0.0f;
        while (g + 4 <= gend) {
            if (g + 4 > sbase + 64) restage(g);
            int b = g - sbase;
            float4 A0 = srec[w][b + 0][0], B0 = srec[w][b + 0][1];
            float4 A1 = srec[w][b + 1][0], B1 = srec[w][b + 1][1];
            float4 A2 = srec[w][b + 2][0], B2 = srec[w][b + 2][1];
            float4 A3 = srec[w][b + 3][0], B3 = srec[w][b + 3][1];
            int s0 = __builtin_amdgcn_readfirstlane(__float_as_int(B0.w));
            int s1 = __builtin_amdgcn_readfirstlane(__float_as_int(B1.w));
            int s2 = __builtin_amdgcn_readfirstlane(__float_as_int(B2.w));
            int s3 = __builtin_amdgcn_readfirstlane(__float_as_int(B3.w));
            float hv0 = hin[(size_t)s0 * H + lane];
            float hv1 = hin[(size_t)s1 * H + lane];
            float hv2 = hin[(size_t)s2 * H + lane];
            float hv3 = hin[(size_t)s3 * H + lane];
            float p0 = rbe2, p1 = rbe2, p2 = rbe2, p3 = rbe2;
            p0 = fmaf(A0.x, rW[0], p0); p0 = fmaf(A0.y, rW[1], p0);
            p0 = fmaf(A0.z, rW[2], p0); p0 = fmaf(A0.w, rW[3], p0);
            p0 = fmaf(B0.x, rW[4], p0); p0 = fmaf(B0.y, rW[5], p0);
            p0 = fmaf(B0.z, rW[6], p0);
            p1 = fmaf(A1.x, rW[0], p1); p1 = fmaf(A1.y, rW[1], p1);
            p1 = fmaf(A1.z, rW[2], p1); p1 = fmaf(A1.w, rW[3], p1);
            p1 = fmaf(B1.x, rW[4], p1); p1 = fmaf(B1.y, rW[5], p1);
            p1 = fmaf(B1.z, rW[6], p1);
            p2 = fmaf(A2.x, rW[0], p2); p2 = fmaf(A2.y, rW[1], p2);
            p2 = fmaf(A2.z, rW[2], p2); p2 = fmaf(A2.w, rW[3], p2);
            p2 = fmaf(B2.x, rW[4], p2); p2 = fmaf(B2.y, rW[5], p2);
            p2 = fmaf(B2.z, rW[6], p2);
            p3 = fmaf(A3.x, rW[0], p3); p3 = fmaf(A3.y, rW[1], p3);
            p3 = fmaf(A3.z, rW[2], p3); p3 = fmaf(A3.w, rW[3], p3);
            p3 = fmaf(B3.x, rW[4], p3); p3 = fmaf(B3.y, rW[5], p3);
            p3 = fmaf(B3.z, rW[6], p3);
            acc += fmaxf(hv0 + p0, 0.0f);
            acc += fmaxf(hv1 + p1, 0.0f);
            acc += fmaxf(hv2 + p2, 0.0f);
            acc += fmaxf(hv3 + p3, 0.0f);
            g += 4;
        }
        while (g < gend) {
            if (g >= sbase + 64) restage(g);
            int b = g - sbase;
            float4 A = srec[w][b][0], B = srec[w][b][1];
            int s = __builtin_amdgcn_readfirstlane(__float_as_int(B.w));
            float hv = hin[(size_t)s * H + lane];
            float p = rbe2;
            p = fmaf(A.x, rW[0], p); p = fmaf(A.y, rW[1], p);
            p = fmaf(A.z, rW[2], p); p = fmaf(A.w, rW[3], p);
            p = fmaf(B.x, rW[4], p); p = fmaf(B.y, rW[5], p);
            p = fmaf(B.z, rW[6], p);
            acc += fmaxf(hv + p, 0.0f);
            g++;
        }
        // wave-synchronous float4 row store to d_out staging
        stg[w][lane] = acc;
        if (lane < 16) {
            float4 v = make_float4(stg[w][lane * 4 + 0], stg[w][lane * 4 + 1],
                                   stg[w][lane * 4 + 2], stg[w][lane * 4 + 3]);
            agg4[(size_t)n * 16 + lane] = v;
        }
    }
}

// ---------------- conv2 stage B: per-node MLP 64->64->64, in-place on hA ----
__global__ void conv2_node(float* __restrict__ hA, const float* __restrict__ agg2,
                           const float* __restrict__ W21, const float* __restrict__ b21,
                           const float* __restrict__ W22, const float* __restrict__ b22,
                           const float* __restrict__ eps2) {
    __shared__ float sW21[H * H], sW22[H * H];
    __shared__ float sh2[4][H], st[4][H];
    int tid = threadIdx.x;
    for (int i = tid; i < H * H; i += 256) { sW21[i] = W21[i]; sW22[i] = W22[i]; }
    int sub = tid >> 6, lane = tid & 63;
    float e = eps2[0];
    float bb21 = b21[lane], bb22 = b22[lane];
    __syncthreads();
#pragma unroll
    for (int it = 0; it < C2_NPB / 4; it++) {
        int n = blockIdx.x * C2_NPB + it * 4 + sub;
        float hv = hA[(size_t)n * H + lane];
        sh2[sub][lane] = fmaf(e, hv, hv) + agg2[(size_t)n * H + lane];
        __syncthreads();
        float acc = bb21;
#pragma unroll
        for (int j = 0; j < H; j++) acc = fmaf(sh2[sub][j], sW21[j * H + lane], acc);
        st[sub][lane] = acc > 0.0f ? acc : 0.0f;
        __syncthreads();
        acc = bb22;
#pragma unroll
        for (int j = 0; j < H; j++) acc = fmaf(st[sub][j], sW22[j * H + lane], acc);
        hA[(size_t)n * H + lane] = acc > 0.0f ? acc : 0.0f;
        __syncthreads();
    }
}

// ---------------- heads: one 8-node tile per block, no serial loop ----------
// 12500 blocks (~49 queued/CU) -> throughput-shaped. mu/lv GEMVs + threefry z;
// LDS-staged cooperative float4 stores to d_out; dword z copy to ws for pool.
__global__ void heads_fz2(const float* __restrict__ hA,
                          const float* __restrict__ Wmu, const float* __restrict__ bmu,
                          const float* __restrict__ Wlv, const float* __restrict__ blv,
                          float4* __restrict__ out4, float* __restrict__ zws) {
    __shared__ float sWmu[H * LAT], sWlv[H * LAT];
    __shared__ float sh[HD_NPB][H];
    __shared__ float sz[HD_NPB][LAT], smu[HD_NPB][LAT], slv[HD_NPB][LAT];
    int tid = threadIdx.x;
    for (int i = tid; i < H * LAT; i += 256) { sWmu[i] = Wmu[i]; sWlv[i] = Wlv[i]; }
    int sub = tid >> 5, lane = tid & 31;
    int base = blockIdx.x * HD_NPB;
#pragma unroll
    for (int i = tid; i < HD_NPB * H; i += 256)
        sh[i >> 6][i & 63] = hA[(size_t)(base + (i >> 6)) * H + (i & 63)];
    __syncthreads();
    int n = base + sub;
    float mu = bmu[lane], lv = blv[lane];
#pragma unroll
    for (int j = 0; j < H; j++) {
        float hv = sh[sub][j];
        mu = fmaf(hv, sWmu[j * LAT + lane], mu);
        lv = fmaf(hv, sWlv[j * LAT + lane], lv);
    }
    int i = n * LAT + lane;
    uint32_t x0 = 0u, x1 = (uint32_t)i;
    threefry2x32_42(x0, x1);
    uint32_t bits = x0 ^ x1;
    float f = __uint_as_float((bits >> 9) | 0x3F800000u) - 1.0f;
    const float lo = -0.99999994f;
    float u = fmaxf(lo, fmaf(f, 2.0f, lo));
    float noise = 1.41421356237309515f * erfinv_f32(u);
    float z = fmaf(noise, expf(0.5f * lv), mu);
    sz[sub][lane] = z; smu[sub][lane] = mu; slv[sub][lane] = lv;
    zws[i] = z;
    __syncthreads();
    if (tid < 192) {
        int grp = tid >> 6;                 // 0=z, 1=mu, 2=lv
        int q = tid & 63;                   // float4 index within 8-node tile
        int nl = q >> 3, f4 = q & 7;
        const float* s = (grp == 0) ? &sz[0][0] : (grp == 1) ? &smu[0][0] : &slv[0][0];
        float4 v = ((const float4*)s)[q];
        out4[(size_t)grp * (NZ / 4) + (size_t)(base + nl) * 8 + f4] = v;
    }
}

// ---------------- pool + logits: float4 gathers of z from ws; batch SORTED --
__global__ void pool_logits_k(const float4* __restrict__ z4, const int* __restrict__ batch,
                              const float* __restrict__ Wc, const float* __restrict__ bc,
                              float* __restrict__ out) {
    int g = blockIdx.x;
    int tid = threadIdx.x;
    int sub = tid >> 3, slot = tid & 7;
    __shared__ float4 acc4[32][8];
    __shared__ float emb[LAT];
    int lo = 0, hi = N_NODES;
    while (lo < hi) { int mid = (lo + hi) >> 1; if (batch[mid] < g) lo = mid + 1; else hi = mid; }
    int start = lo;
    hi = N_NODES;
    while (lo < hi) { int mid = (lo + hi) >> 1; if (batch[mid] < g + 1) lo = mid + 1; else hi = mid; }
    int end = lo;
    float4 a = make_float4(0.f, 0.f, 0.f, 0.f);
    for (int n = start + sub; n < end; n += 32) {
        float4 v = z4[(size_t)n * (LAT / 4) + slot];
        a.x += v.x; a.y += v.y; a.z += v.z; a.w += v.w;
    }
    acc4[sub][slot] = a;
    __syncthreads();
    if (tid < 8) {
        float4 s4 = acc4[0][tid];
        for (int k = 1; k < 32; k++) {
            s4.x += acc4[k][tid].x; s4.y += acc4[k][tid].y;
            s4.z += acc4[k][tid].z; s4.w += acc4[k][tid].w;
        }
        float invc = 1.0f / fmaxf((float)(end - start), 1.0f);
        emb[tid * 4 + 0] = s4.x * invc; emb[tid * 4 + 1] = s4.y * invc;
        emb[tid * 4 + 2] = s4.z * invc; emb[tid * 4 + 3] = s4.w * invc;
    }
    __syncthreads();
    if (tid < NC) {
        float r = bc[tid];
#pragma unroll
        for (int l = 0; l < LAT; l++) r = fmaf(emb[l], Wc[l * NC + tid], r);
        out[g * NC + tid] = r;
    }
}

extern "C" void kernel_launch(void* const* d_in, const int* in_sizes, int n_in,
                              void* d_out, int out_size, void* d_ws, size_t ws_size,
                              hipStream_t stream) {
    const float* x     = (const float*)d_in[0];
    const int*   ei    = (const int*)d_in[1];
    const float* ea    = (const float*)d_in[2];
    const int*   batch = (const int*)d_in[3];
    const float* We1   = (const float*)d_in[4];
    const float* be1   = (const float*)d_in[5];
    const float* W11   = (const float*)d_in[6];
    const float* b11   = (const float*)d_in[7];
    const float* W12   = (const float*)d_in[8];
    const float* b12   = (const float*)d_in[9];
    const float* eps1  = (const float*)d_in[10];
    const float* We2   = (const float*)d_in[11];
    const float* be2   = (const float*)d_in[12];
    const float* W21   = (const float*)d_in[13];
    const float* b21   = (const float*)d_in[14];
    const float* W22   = (const float*)d_in[15];
    const float* b22   = (const float*)d_in[16];
    const float* eps2  = (const float*)d_in[17];
    const float* Wmu   = (const float*)d_in[18];
    const float* bmu   = (const float*)d_in[19];
    const float* Wlv   = (const float*)d_in[20];
    const float* blv   = (const float*)d_in[21];
    const float* Wc    = (const float*)d_in[22];
    const float* bc    = (const float*)d_in[23];

    // ws layout (46.0 MB < proven 51.6 MB budget).
    //   [deg N][off N][cur N][bsum 512]      ints   1.20 MB
    //   [rec8 E int2]                               12.80 MB  (dead after conv2_agg -> zws)
    //   [m1s E float]                                6.40 MB
    //   [hA  N*H float]                             25.60 MB  (conv1 out, conv2 in-place)
    // d_out staging: agg2 rows [0..25.6MB) via float4, dead after conv2_node,
    // then overwritten by heads' final z/mu/lv float4 stores.
    int*   deg  = (int*)d_ws;
    int*   off  = deg + N_NODES;
    int*   cur  = off + N_NODES;
    int*   bsum = cur + N_NODES;
    int2*  rec8 = (int2*)(bsum + 512);
    float* m1s  = (float*)(rec8 + N_EDGES);
    float* hA   = m1s + N_EDGES;
    float* zws  = (float*)rec8;             // reuse: rec8 dead after conv2_agg
    float* agg2 = (float*)d_out;            // staging rows in d_out
    float* outf = (float*)d_out;

    hipMemsetAsync(deg, 0, N_NODES * sizeof(int), stream);

    const int* src = ei;
    const int* dst = ei + N_EDGES;

    hist_k<<<N_EDGES / 256, 256, 0, stream>>>(dst, deg);
    scan1_k<<<NB_SCAN, 256, 0, stream>>>(deg, bsum);
    scan2_k<<<1, 512, 0, stream>>>(bsum);
    scan3_k<<<NB_SCAN, 256, 0, stream>>>(deg, bsum, off, cur);
    scatter_k<<<N_EDGES / 256, 256, 0, stream>>>(x, src, dst, ea, We1, be1, cur, rec8, m1s);
    conv1_fused<<<N_NODES / (4 * NPW1), 256, 0, stream>>>(
        x, m1s, off, cur, W11, b11, W12, b12, eps1, hA);
    conv2_agg<<<N_NODES / (4 * NPW2), 256, 0, stream>>>(
        hA, rec8, ea, off, cur, We2, be2, (float4*)agg2);
    conv2_node<<<N_NODES / C2_NPB, 256, 0, stream>>>(hA, agg2, W21, b21, W22, b22, eps2);
    heads_fz2<<<N_NODES / HD_NPB, 256, 0, stream>>>(
        hA, Wmu, bmu, Wlv, blv, (float4*)outf, zws);
    pool_logits_k<<<NG, 256, 0, stream>>>((const float4*)zws, batch, Wc, bc,
                                          outf + 3 * (size_t)NZ);
}

// Round 6
// 864.305 us; speedup vs baseline: 1.3044x; 1.0006x over previous
//
#include <hip/hip_runtime.h>
#include <stdint.h>

#define N_NODES 100000
#define N_EDGES 1600000
#define EAD 7
#define H 64
#define LAT 32
#define NG 512
#define NC 6
#define NZ (N_NODES * LAT)

#define NB_SCAN 391            // ceil(N_NODES/256)
#define NPW1 4                 // nodes per wave, conv1 (6250 blocks)
#define NPW2 2                 // nodes per wave, conv2_agg (12500 blocks, Path B)
#define NPW2F 2                // nodes per wave, conv2_fused (12500 blocks, Path A)
#define C2_NPB 32              // nodes per block, conv2_node (Path B)
#define HD_NPB 8               // nodes per block, heads (12500 blocks)

static_assert(N_NODES % (4 * NPW1) == 0, "conv1 grid exact");
static_assert(N_NODES % (4 * NPW2) == 0, "conv2_agg grid exact");
static_assert(N_NODES % (4 * NPW2F) == 0, "conv2_fused grid exact");
static_assert(N_NODES % C2_NPB == 0, "conv2_node grid exact");
static_assert(N_NODES % HD_NPB == 0, "heads grid exact");
static_assert(N_EDGES % 256 == 0, "edge grid exact");

// ---------------- Threefry-2x32-20, key = (0, 42)  (jax.random.key(42)) ----
__device__ __forceinline__ void threefry2x32_42(uint32_t& x0, uint32_t& x1) {
    const uint32_t k0 = 0u, k1 = 42u;
    const uint32_t k2 = k0 ^ k1 ^ 0x1BD11BDAu;
    x0 += k0; x1 += k1;
#define TF_ROUND(r) { x0 += x1; x1 = (x1 << (r)) | (x1 >> (32 - (r))); x1 ^= x0; }
    TF_ROUND(13) TF_ROUND(15) TF_ROUND(26) TF_ROUND(6)
    x0 += k1; x1 += k2 + 1u;
    TF_ROUND(17) TF_ROUND(29) TF_ROUND(16) TF_ROUND(24)
    x0 += k2; x1 += k0 + 2u;
    TF_ROUND(13) TF_ROUND(15) TF_ROUND(26) TF_ROUND(6)
    x0 += k0; x1 += k1 + 3u;
    TF_ROUND(17) TF_ROUND(29) TF_ROUND(16) TF_ROUND(24)
    x0 += k1; x1 += k2 + 4u;
    TF_ROUND(13) TF_ROUND(15) TF_ROUND(26) TF_ROUND(6)
    x0 += k2; x1 += k0 + 5u;
#undef TF_ROUND
}

// XLA f32 ErfInv (Giles): matches jax.lax.erf_inv on f32
__device__ __forceinline__ float erfinv_f32(float x) {
    float w = -log1pf(-x * x);
    float p;
    if (w < 5.0f) {
        w = w - 2.5f;
        p = 2.81022636e-08f;
        p = fmaf(p, w, 3.43273939e-07f);
        p = fmaf(p, w, -3.5233877e-06f);
        p = fmaf(p, w, -4.39150654e-06f);
        p = fmaf(p, w, 0.00021858087f);
        p = fmaf(p, w, -0.00125372503f);
        p = fmaf(p, w, -0.00417768164f);
        p = fmaf(p, w, 0.246640727f);
        p = fmaf(p, w, 1.50140941f);
    } else {
        w = sqrtf(w) - 3.0f;
        p = -0.000200214257f;
        p = fmaf(p, w, 0.000100950558f);
        p = fmaf(p, w, 0.00134934322f);
        p = fmaf(p, w, -0.00367342844f);
        p = fmaf(p, w, 0.00573950773f);
        p = fmaf(p, w, -0.0076224613f);
        p = fmaf(p, w, 0.00943887047f);
        p = fmaf(p, w, 1.00167406f);
        p = fmaf(p, w, 2.83297682f);
    }
    return p * x;
}

// ---------------- CSR build: histogram of dst -------------------------------
__global__ void hist_k(const int* __restrict__ dst, int* __restrict__ deg) {
    int e = blockIdx.x * blockDim.x + threadIdx.x;
    if (e < N_EDGES) atomicAdd(&deg[dst[e]], 1);
}

// ---------------- CSR build: 3-pass exclusive scan over deg -----------------
__global__ void scan1_k(const int* __restrict__ deg, int* __restrict__ bsum) {
    __shared__ int sv[256];
    int t = threadIdx.x, i = blockIdx.x * 256 + t;
    sv[t] = (i < N_NODES) ? deg[i] : 0;
    __syncthreads();
    for (int o = 128; o > 0; o >>= 1) {
        if (t < o) sv[t] += sv[t + o];
        __syncthreads();
    }
    if (t == 0) bsum[blockIdx.x] = sv[0];
}

__global__ void scan2_k(int* __restrict__ bsum) {
    __shared__ int sv[512];
    int t = threadIdx.x;
    int v = (t < NB_SCAN) ? bsum[t] : 0;
    sv[t] = v;
    __syncthreads();
    for (int o = 1; o < 512; o <<= 1) {
        int a = (t >= o) ? sv[t - o] : 0;
        __syncthreads();
        sv[t] += a;
        __syncthreads();
    }
    if (t < NB_SCAN) bsum[t] = sv[t] - v;   // exclusive block offsets
}

__global__ void scan3_k(const int* __restrict__ deg, const int* __restrict__ bsum,
                        int* __restrict__ off, int* __restrict__ cur) {
    __shared__ int sv[256];
    int t = threadIdx.x, i = blockIdx.x * 256 + t;
    int v = (i < N_NODES) ? deg[i] : 0;
    sv[t] = v;
    __syncthreads();
    for (int o = 1; o < 256; o <<= 1) {
        int a = (t >= o) ? sv[t - o] : 0;
        __syncthreads();
        sv[t] += a;
        __syncthreads();
    }
    if (i < N_NODES) {
        int s = bsum[blockIdx.x] + sv[t] - v;
        off[i] = s;
        cur[i] = s;   // cursor; after scatter_k, cur[i] == segment end
    }
}

// ---------------- CSR build: scatter edges into dst-sorted order ------------
__global__ void scatter_k(const float* __restrict__ x, const int* __restrict__ src,
                          const int* __restrict__ dst, const float* __restrict__ ea,
                          const float* __restrict__ We1, const float* __restrict__ be1,
                          int* __restrict__ cur, int2* __restrict__ rec8,
                          float* __restrict__ m1s) {
    int e = blockIdx.x * blockDim.x + threadIdx.x;
    if (e >= N_EDGES) return;
    int s = src[e], d = dst[e];
    const float* ep = ea + (size_t)e * EAD;
    float p = be1[0];
#pragma unroll
    for (int k = 0; k < EAD; k++) p = fmaf(ep[k], We1[k], p);
    float m = x[s] + p;
    m = m > 0.0f ? m : 0.0f;
    int pos = atomicAdd(&cur[d], 1);
    rec8[pos] = make_int2(s, e);
    m1s[pos] = m;
}

// ---------------- conv1: segmented sum of m1 + fused MLP 1->64->64 ----------
__global__ void conv1_fused(const float* __restrict__ x, const float* __restrict__ m1s,
                            const int* __restrict__ off, const int* __restrict__ cur,
                            const float* __restrict__ W11, const float* __restrict__ b11,
                            const float* __restrict__ W12, const float* __restrict__ b12,
                            const float* __restrict__ eps1, float* __restrict__ hA) {
    __shared__ float sW12[H * H];
    __shared__ float stg[4][H];
    int tid = threadIdx.x;
    for (int i = tid; i < H * H; i += 256) sW12[i] = W12[i];
    int w = tid >> 6, lane = tid & 63;
    float rW11 = W11[lane], rb11 = b11[lane], rb12 = b12[lane], er = eps1[0];
    __syncthreads();
    int n0 = (blockIdx.x * 4 + w) * NPW1;
#pragma unroll
    for (int ni = 0; ni < NPW1; ni++) {
        int n = n0 + ni;
        int g0 = off[n], g1 = cur[n];
        float agg = 0.0f;
        for (int j = g0 + lane; j < g1; j += 64) agg += m1s[j];
#pragma unroll
        for (int o = 32; o > 0; o >>= 1) agg += __shfl_xor(agg, o, 64);
        float xv = x[n];
        float h1 = fmaf(er, xv, xv) + agg;
        float t = fmaf(h1, rW11, rb11);
        t = t > 0.0f ? t : 0.0f;
        stg[w][lane] = t;                  // intra-wave staging (lockstep)
        float acc = rb12;
#pragma unroll
        for (int j = 0; j < H; j++) acc = fmaf(stg[w][j], sW12[j * H + lane], acc);
        hA[(size_t)n * H + lane] = acc > 0.0f ? acc : 0.0f;
    }
}

// ---------------- Path A: conv2 fully fused (gather + MLP), hB in ws --------
// r1-proven kernel (ran correct on HW), NPW2F=2 for throughput shape.
// hin != hout -> race-free. No d_out traffic at all.
__global__ void conv2_fused(const float* __restrict__ hin, const int2* __restrict__ rec8,
                            const float* __restrict__ ea,
                            const int* __restrict__ off, const int* __restrict__ cur,
                            const float* __restrict__ We2, const float* __restrict__ be2,
                            const float* __restrict__ W21, const float* __restrict__ b21,
                            const float* __restrict__ W22, const float* __restrict__ b22,
                            const float* __restrict__ eps2, float* __restrict__ hB) {
    __shared__ float sW21[H * H], sW22[H * H];
    __shared__ float4 srec[4][64][2];
    __shared__ float stg[4][H];
    int tid = threadIdx.x;
    for (int i = tid; i < H * H; i += 256) { sW21[i] = W21[i]; sW22[i] = W22[i]; }
    int w = tid >> 6, lane = tid & 63;
    float rW[EAD];
#pragma unroll
    for (int k = 0; k < EAD; k++) rW[k] = We2[k * H + lane];
    float rbe2 = be2[lane], rb21 = b21[lane], rb22 = b22[lane], er = eps2[0];
    __syncthreads();

    int n0 = (blockIdx.x * 4 + w) * NPW2F;
    int eend = cur[n0 + NPW2F - 1];
    int sbase = -(1 << 30);

    auto restage = [&](int g) {
        sbase = g;
        int cnt = eend - g; cnt = cnt > 64 ? 64 : cnt;
        float a0 = 0, a1 = 0, a2 = 0, a3 = 0, a4 = 0, a5 = 0, a6 = 0;
        int s = 0;
        if (lane < cnt) {
            int2 r = rec8[g + lane];
            s = r.x;
            const float* ep = ea + (size_t)r.y * EAD;
            a0 = ep[0]; a1 = ep[1]; a2 = ep[2]; a3 = ep[3];
            a4 = ep[4]; a5 = ep[5]; a6 = ep[6];
        }
        srec[w][lane][0] = make_float4(a0, a1, a2, a3);
        srec[w][lane][1] = make_float4(a4, a5, a6, __int_as_float(s));
    };

#pragma unroll
    for (int ni = 0; ni < NPW2F; ni++) {
        int n = n0 + ni;
        int g = off[n], gend = cur[n];
        float acc = 0.0f;
        while (g + 4 <= gend) {
            if (g + 4 > sbase + 64) restage(g);
            int b = g - sbase;
            float4 A0 = srec[w][b + 0][0], B0 = srec[w][b + 0][1];
            float4 A1 = srec[w][b + 1][0], B1 = srec[w][b + 1][1];
            float4 A2 = srec[w][b + 2][0], B2 = srec[w][b + 2][1];
            float4 A3 = srec[w][b + 3][0], B3 = srec[w][b + 3][1];
            int s0 = __builtin_amdgcn_readfirstlane(__float_as_int(B0.w));
            int s1 = __builtin_amdgcn_readfirstlane(__float_as_int(B1.w));
            int s2 = __builtin_amdgcn_readfirstlane(__float_as_int(B2.w));
            int s3 = __builtin_amdgcn_readfirstlane(__float_as_int(B3.w));
            float hv0 = hin[(size_t)s0 * H + lane];
            float hv1 = hin[(size_t)s1 * H + lane];
            float hv2 = hin[(size_t)s2 * H + lane];
            float hv3 = hin[(size_t)s3 * H + lane];
            float p0 = rbe2, p1 = rbe2, p2 = rbe2, p3 = rbe2;
            p0 = fmaf(A0.x, rW[0], p0); p0 = fmaf(A0.y, rW[1], p0);
            p0 = fmaf(A0.z, rW[2], p0); p0 = fmaf(A0.w, rW[3], p0);
            p0 = fmaf(B0.x, rW[4], p0); p0 = fmaf(B0.y, rW[5], p0);
            p0 = fmaf(B0.z, rW[6], p0);
            p1 = fmaf(A1.x, rW[0], p1); p1 = fmaf(A1.y, rW[1], p1);
            p1 = fmaf(A1.z, rW[2], p1); p1 = fmaf(A1.w, rW[3], p1);
            p1 = fmaf(B1.x, rW[4], p1); p1 = fmaf(B1.y, rW[5], p1);
            p1 = fmaf(B1.z, rW[6], p1);
            p2 = fmaf(A2.x, rW[0], p2); p2 = fmaf(A2.y, rW[1], p2);
            p2 = fmaf(A2.z, rW[2], p2); p2 = fmaf(A2.w, rW[3], p2);
            p2 = fmaf(B2.x, rW[4], p2); p2 = fmaf(B2.y, rW[5], p2);
            p2 = fmaf(B2.z, rW[6], p2);
            p3 = fmaf(A3.x, rW[0], p3); p3 = fmaf(A3.y, rW[1], p3);
            p3 = fmaf(A3.z, rW[2], p3); p3 = fmaf(A3.w, rW[3], p3);
            p3 = fmaf(B3.x, rW[4], p3); p3 = fmaf(B3.y, rW[5], p3);
            p3 = fmaf(B3.z, rW[6], p3);
            acc += fmaxf(hv0 + p0, 0.0f);
            acc += fmaxf(hv1 + p1, 0.0f);
            acc += fmaxf(hv2 + p2, 0.0f);
            acc += fmaxf(hv3 + p3, 0.0f);
            g += 4;
        }
        while (g < gend) {
            if (g >= sbase + 64) restage(g);
            int b = g - sbase;
            float4 A = srec[w][b][0], B = srec[w][b][1];
            int s = __builtin_amdgcn_readfirstlane(__float_as_int(B.w));
            float hv = hin[(size_t)s * H + lane];
            float p = rbe2;
            p = fmaf(A.x, rW[0], p); p = fmaf(A.y, rW[1], p);
            p = fmaf(A.z, rW[2], p); p = fmaf(A.w, rW[3], p);
            p = fmaf(B.x, rW[4], p); p = fmaf(B.y, rW[5], p);
            p = fmaf(B.z, rW[6], p);
            acc += fmaxf(hv + p, 0.0f);
            g++;
        }
        // fused 2-layer MLP (wave-synchronous LDS staging)
        float hself = hin[(size_t)n * H + lane];
        float h2 = fmaf(er, hself, hself) + acc;
        stg[w][lane] = h2;
        float t = rb21;
#pragma unroll
        for (int j = 0; j < H; j++) t = fmaf(stg[w][j], sW21[j * H + lane], t);
        t = t > 0.0f ? t : 0.0f;
        stg[w][lane] = t;
        float o2 = rb22;
#pragma unroll
        for (int j = 0; j < H; j++) o2 = fmaf(stg[w][j], sW22[j * H + lane], o2);
        hB[(size_t)n * H + lane] = o2 > 0.0f ? o2 : 0.0f;
    }
}

// ---------------- Path B: conv2 stage A, gather -> agg rows (d_out staging) -
__global__ void conv2_agg(const float* __restrict__ hin, const int2* __restrict__ rec8,
                          const float* __restrict__ ea,
                          const int* __restrict__ off, const int* __restrict__ cur,
                          const float* __restrict__ We2, const float* __restrict__ be2,
                          float4* __restrict__ agg4) {
    __shared__ float4 srec[4][64][2];
    __shared__ float stg[4][H];
    int tid = threadIdx.x;
    int w = tid >> 6, lane = tid & 63;
    float rW[EAD];
#pragma unroll
    for (int k = 0; k < EAD; k++) rW[k] = We2[k * H + lane];
    float rbe2 = be2[lane];

    int n0 = (blockIdx.x * 4 + w) * NPW2;
    int eend = cur[n0 + NPW2 - 1];
    int sbase = -(1 << 30);

    auto restage = [&](int g) {
        sbase = g;
        int cnt = eend - g; cnt = cnt > 64 ? 64 : cnt;
        float a0 = 0, a1 = 0, a2 = 0, a3 = 0, a4 = 0, a5 = 0, a6 = 0;
        int s = 0;
        if (lane < cnt) {
            int2 r = rec8[g + lane];
            s = r.x;
            const float* ep = ea + (size_t)r.y * EAD;
            a0 = ep[0]; a1 = ep[1]; a2 = ep[2]; a3 = ep[3];
            a4 = ep[4]; a5 = ep[5]; a6 = ep[6];
        }
        srec[w][lane][0] = make_float4(a0, a1, a2, a3);
        srec[w][lane][1] = make_float4(a4, a5, a6, __int_as_float(s));
    };

#pragma unroll
    for (int ni = 0; ni < NPW2; ni++) {
        int n = n0 + ni;
        int g = off[n], gend = cur[n];
        float acc = 0.0f;
        while (g + 4 <= gend) {
            if (g + 4 > sbase + 64) restage(g);
            int b = g - sbase;
            float4 A0 = srec[w][b + 0][0], B0 = srec[w][b + 0][1];
            float4 A1 = srec[w][b + 1][0], B1 = srec[w][b + 1][1];
            float4 A2 = srec[w][b + 2][0], B2 = srec[w][b + 2][1];
            float4 A3 = srec[w][b + 3][0], B3 = srec[w][b + 3][1];
            int s0 = __builtin_amdgcn_readfirstlane(__float_as_int(B0.w));
            int s1 = __builtin_amdgcn_readfirstlane(__float_as_int(B1.w));
            int s2 = __builtin_amdgcn_readfirstlane(__float_as_int(B2.w));
            int s3 = __builtin_amdgcn_readfirstlane(__float_as_int(B3.w));
            float hv0 = hin[(size_t)s0 * H + lane];
            float hv1 = hin[(size_t)s1 * H + lane];
            float hv2 = hin[(size_t)s2 * H + lane];
            float hv3 = hin[(size_t)s3 * H + lane];
            float p0 = rbe2, p1 = rbe2, p2 = rbe2, p3 = rbe2;
            p0 = fmaf(A0.x, rW[0], p0); p0 = fmaf(A0.y, rW[1], p0);
            p0 = fmaf(A0.z, rW[2], p0); p0 = fmaf(A0.w, rW[3], p0);
            p0 = fmaf(B0.x, rW[4], p0); p0 = fmaf(B0.y, rW[5], p0);
            p0 = fmaf(B0.z, rW[6], p0);
            p1 = fmaf(A1.x, rW[0], p1); p1 = fmaf(A1.y, rW[1], p1);
            p1 = fmaf(A1.z, rW[2], p1); p1 = fmaf(A1.w, rW[3], p1);
            p1 = fmaf(B1.x, rW[4], p1); p1 = fmaf(B1.y, rW[5], p1);
            p1 = fmaf(B1.z, rW[6], p1);
            p2 = fmaf(A2.x, rW[0], p2); p2 = fmaf(A2.y, rW[1], p2);
            p2 = fmaf(A2.z, rW[2], p2); p2 = fmaf(A2.w, rW[3], p2);
            p2 = fmaf(B2.x, rW[4], p2); p2 = fmaf(B2.y, rW[5], p2);
            p2 = fmaf(B2.z, rW[6], p2);
            p3 = fmaf(A3.x, rW[0], p3); p3 = fmaf(A3.y, rW[1], p3);
            p3 = fmaf(A3.z, rW[2], p3); p3 = fmaf(A3.w, rW[3], p3);
            p3 = fmaf(B3.x, rW[4], p3); p3 = fmaf(B3.y, rW[5], p3);
            p3 = fmaf(B3.z, rW[6], p3);
            acc += fmaxf(hv0 + p0, 0.0f);
            acc += fmaxf(hv1 + p1, 0.0f);
            acc += fmaxf(hv2 + p2, 0.0f);
            acc += fmaxf(hv3 + p3, 0.0f);
            g += 4;
        }
        while (g < gend) {
            if (g >= sbase + 64) restage(g);
            int b = g - sbase;
            float4 A = srec[w][b][0], B = srec[w][b][1];
            int s = __builtin_amdgcn_readfirstlane(__float_as_int(B.w));
            float hv = hin[(size_t)s * H + lane];
            float p = rbe2;
            p = fmaf(A.x, rW[0], p); p = fmaf(A.y, rW[1], p);
            p = fmaf(A.z, rW[2], p); p = fmaf(A.w, rW[3], p);
            p = fmaf(B.x, rW[4], p); p = fmaf(B.y, rW[5], p);
            p = fmaf(B.z, rW[6], p);
            acc += fmaxf(hv + p, 0.0f);
            g++;
        }
        stg[w][lane] = acc;
        if (lane < 16) {
            float4 v = make_float4(stg[w][lane * 4 + 0], stg[w][lane * 4 + 1],
                                   stg[w][lane * 4 + 2], stg[w][lane * 4 + 3]);
            agg4[(size_t)n * 16 + lane] = v;
        }
    }
}

// ---------------- Path B: conv2 stage B, per-node MLP in-place on hA --------
__global__ void conv2_node(float* __restrict__ hA, const float* __restrict__ agg2,
                           const float* __restrict__ W21, const float* __restrict__ b21,
                           const float* __restrict__ W22, const float* __restrict__ b22,
                           const float* __restrict__ eps2) {
    __shared__ float sW21[H * H], sW22[H * H];
    __shared__ float sh2[4][H], st[4][H];
    int tid = threadIdx.x;
    for (int i = tid; i < H * H; i += 256) { sW21[i] = W21[i]; sW22[i] = W22[i]; }
    int sub = tid >> 6, lane = tid & 63;
    float e = eps2[0];
    float bb21 = b21[lane], bb22 = b22[lane];
    __syncthreads();
#pragma unroll
    for (int it = 0; it < C2_NPB / 4; it++) {
        int n = blockIdx.x * C2_NPB + it * 4 + sub;
        float hv = hA[(size_t)n * H + lane];
        sh2[sub][lane] = fmaf(e, hv, hv) + agg2[(size_t)n * H + lane];
        __syncthreads();
        float acc = bb21;
#pragma unroll
        for (int j = 0; j < H; j++) acc = fmaf(sh2[sub][j], sW21[j * H + lane], acc);
        st[sub][lane] = acc > 0.0f ? acc : 0.0f;
        __syncthreads();
        acc = bb22;
#pragma unroll
        for (int j = 0; j < H; j++) acc = fmaf(st[sub][j], sW22[j * H + lane], acc);
        hA[(size_t)n * H + lane] = acc > 0.0f ? acc : 0.0f;
        __syncthreads();
    }
}

// ---------------- heads: one 8-node tile per block --------------------------
// mu/lv GEMVs + threefry z; cooperative float4 stores to d_out AND zws.
__global__ void heads_fz2(const float* __restrict__ hsrc,
                          const float* __restrict__ Wmu, const float* __restrict__ bmu,
                          const float* __restrict__ Wlv, const float* __restrict__ blv,
                          float4* __restrict__ out4, float4* __restrict__ zws4) {
    __shared__ float sWmu[H * LAT], sWlv[H * LAT];
    __shared__ float sh[HD_NPB][H];
    __shared__ float sz[HD_NPB][LAT], smu[HD_NPB][LAT], slv[HD_NPB][LAT];
    int tid = threadIdx.x;
    for (int i = tid; i < H * LAT; i += 256) { sWmu[i] = Wmu[i]; sWlv[i] = Wlv[i]; }
    int sub = tid >> 5, lane = tid & 31;
    int base = blockIdx.x * HD_NPB;
#pragma unroll
    for (int i = tid; i < HD_NPB * H; i += 256)
        sh[i >> 6][i & 63] = hsrc[(size_t)(base + (i >> 6)) * H + (i & 63)];
    __syncthreads();
    int n = base + sub;
    float mu = bmu[lane], lv = blv[lane];
#pragma unroll
    for (int j = 0; j < H; j++) {
        float hv = sh[sub][j];
        mu = fmaf(hv, sWmu[j * LAT + lane], mu);
        lv = fmaf(hv, sWlv[j * LAT + lane], lv);
    }
    int i = n * LAT + lane;
    uint32_t x0 = 0u, x1 = (uint32_t)i;
    threefry2x32_42(x0, x1);
    uint32_t bits = x0 ^ x1;
    float f = __uint_as_float((bits >> 9) | 0x3F800000u) - 1.0f;
    const float lo = -0.99999994f;
    float u = fmaxf(lo, fmaf(f, 2.0f, lo));
    float noise = 1.41421356237309515f * erfinv_f32(u);
    float z = fmaf(noise, expf(0.5f * lv), mu);
    sz[sub][lane] = z; smu[sub][lane] = mu; slv[sub][lane] = lv;
    __syncthreads();
    if (tid < 192) {
        int grp = tid >> 6;                 // 0=z, 1=mu, 2=lv
        int q = tid & 63;                   // float4 index within 8-node tile
        int nl = q >> 3, f4 = q & 7;
        const float* s = (grp == 0) ? &sz[0][0] : (grp == 1) ? &smu[0][0] : &slv[0][0];
        float4 v = ((const float4*)s)[q];
        out4[(size_t)grp * (NZ / 4) + (size_t)(base + nl) * 8 + f4] = v;
        if (grp == 0) zws4[(size_t)base * 8 + q] = v;   // float4 z copy for pool
    }
}

// ---------------- pool + logits: float4 gathers of z from ws; batch SORTED --
__global__ void pool_logits_k(const float4* __restrict__ z4, const int* __restrict__ batch,
                              const float* __restrict__ Wc, const float* __restrict__ bc,
                              float* __restrict__ out) {
    int g = blockIdx.x;
    int tid = threadIdx.x;
    int sub = tid >> 3, slot = tid & 7;
    __shared__ float4 acc4[32][8];
    __shared__ float emb[LAT];
    int lo = 0, hi = N_NODES;
    while (lo < hi) { int mid = (lo + hi) >> 1; if (batch[mid] < g) lo = mid + 1; else hi = mid; }
    int start = lo;
    hi = N_NODES;
    while (lo < hi) { int mid = (lo + hi) >> 1; if (batch[mid] < g + 1) lo = mid + 1; else hi = mid; }
    int end = lo;
    float4 a = make_float4(0.f, 0.f, 0.f, 0.f);
    for (int n = start + sub; n < end; n += 32) {
        float4 v = z4[(size_t)n * (LAT / 4) + slot];
        a.x += v.x; a.y += v.y; a.z += v.z; a.w += v.w;
    }
    acc4[sub][slot] = a;
    __syncthreads();
    if (tid < 8) {
        float4 s4 = acc4[0][tid];
        for (int k = 1; k < 32; k++) {
            s4.x += acc4[k][tid].x; s4.y += acc4[k][tid].y;
            s4.z += acc4[k][tid].z; s4.w += acc4[k][tid].w;
        }
        float invc = 1.0f / fmaxf((float)(end - start), 1.0f);
        emb[tid * 4 + 0] = s4.x * invc; emb[tid * 4 + 1] = s4.y * invc;
        emb[tid * 4 + 2] = s4.z * invc; emb[tid * 4 + 3] = s4.w * invc;
    }
    __syncthreads();
    if (tid < NC) {
        float r = bc[tid];
#pragma unroll
        for (int l = 0; l < LAT; l++) r = fmaf(emb[l], Wc[l * NC + tid], r);
        out[g * NC + tid] = r;
    }
}

extern "C" void kernel_launch(void* const* d_in, const int* in_sizes, int n_in,
                              void* d_out, int out_size, void* d_ws, size_t ws_size,
                              hipStream_t stream) {
    const float* x     = (const float*)d_in[0];
    const int*   ei    = (const int*)d_in[1];
    const float* ea    = (const float*)d_in[2];
    const int*   batch = (const int*)d_in[3];
    const float* We1   = (const float*)d_in[4];
    const float* be1   = (const float*)d_in[5];
    const float* W11   = (const float*)d_in[6];
    const float* b11   = (const float*)d_in[7];
    const float* W12   = (const float*)d_in[8];
    const float* b12   = (const float*)d_in[9];
    const float* eps1  = (const float*)d_in[10];
    const float* We2   = (const float*)d_in[11];
    const float* be2   = (const float*)d_in[12];
    const float* W21   = (const float*)d_in[13];
    const float* b21   = (const float*)d_in[14];
    const float* W22   = (const float*)d_in[15];
    const float* b22   = (const float*)d_in[16];
    const float* eps2  = (const float*)d_in[17];
    const float* Wmu   = (const float*)d_in[18];
    const float* bmu   = (const float*)d_in[19];
    const float* Wlv   = (const float*)d_in[20];
    const float* blv   = (const float*)d_in[21];
    const float* Wc    = (const float*)d_in[22];
    const float* bc    = (const float*)d_in[23];

    // ws layout:
    //   [deg N][off N][cur N][bsum 512]      ints   1.20 MB
    //   [rec8 E int2]                               12.80 MB  (zws reuse after conv2)
    //   [m1s E float]                                6.40 MB  (dead after conv1)
    //   [hA  N*H float]                             25.60 MB
    //   [hB  N*H float]  (Path A only)              25.60 MB  -> 71.6 MB total
    // Path A (ws >= 71.6 MB): conv2 fully fused, hB in ws, zero d_out staging.
    // Path B (else, proven 46 MB): agg2 staged in d_out (slow ~125 GB/s writes).
    int*   deg  = (int*)d_ws;
    int*   off  = deg + N_NODES;
    int*   cur  = off + N_NODES;
    int*   bsum = cur + N_NODES;
    int2*  rec8 = (int2*)(bsum + 512);
    float* m1s  = (float*)(rec8 + N_EDGES);
    float* hA   = m1s + N_EDGES;
    float* hB   = hA + (size_t)N_NODES * H;
    float* zws  = (float*)rec8;             // reuse: rec8 dead after conv2
    float* outf = (float*)d_out;

    const size_t PATHA_BYTES =
        (size_t)(3 * N_NODES + 512) * 4 + (size_t)N_EDGES * 12 +
        2 * (size_t)N_NODES * H * 4;        // 71.6 MB

    hipMemsetAsync(deg, 0, N_NODES * sizeof(int), stream);

    const int* src = ei;
    const int* dst = ei + N_EDGES;

    hist_k<<<N_EDGES / 256, 256, 0, stream>>>(dst, deg);
    scan1_k<<<NB_SCAN, 256, 0, stream>>>(deg, bsum);
    scan2_k<<<1, 512, 0, stream>>>(bsum);
    scan3_k<<<NB_SCAN, 256, 0, stream>>>(deg, bsum, off, cur);
    scatter_k<<<N_EDGES / 256, 256, 0, stream>>>(x, src, dst, ea, We1, be1, cur, rec8, m1s);
    conv1_fused<<<N_NODES / (4 * NPW1), 256, 0, stream>>>(
        x, m1s, off, cur, W11, b11, W12, b12, eps1, hA);

    if (ws_size >= PATHA_BYTES) {
        // Path A: fused conv2, no d_out staging round-trip
        conv2_fused<<<N_NODES / (4 * NPW2F), 256, 0, stream>>>(
            hA, rec8, ea, off, cur, We2, be2, W21, b21, W22, b22, eps2, hB);
        heads_fz2<<<N_NODES / HD_NPB, 256, 0, stream>>>(
            hB, Wmu, bmu, Wlv, blv, (float4*)outf, (float4*)zws);
    } else {
        // Path B: staged conv2 via d_out (proven 46 MB footprint)
        float* agg2 = (float*)d_out;
        conv2_agg<<<N_NODES / (4 * NPW2), 256, 0, stream>>>(
            hA, rec8, ea, off, cur, We2, be2, (float4*)agg2);
        conv2_node<<<N_NODES / C2_NPB, 256, 0, stream>>>(hA, agg2, W21, b21, W22, b22, eps2);
        heads_fz2<<<N_NODES / HD_NPB, 256, 0, stream>>>(
            hA, Wmu, bmu, Wlv, blv, (float4*)outf, (float4*)zws);
    }
    pool_logits_k<<<NG, 256, 0, stream>>>((const float4*)zws, batch, Wc, bc,
                                          outf + 3 * (size_t)NZ);
}

// Round 7
// 787.215 us; speedup vs baseline: 1.4321x; 1.0979x over previous
//
#include <hip/hip_runtime.h>
#include <stdint.h>

#define N_NODES 100000
#define N_EDGES 1600000
#define EAD 7
#define H 64
#define LAT 32
#define NG 512
#define NC 6
#define NZ (N_NODES * LAT)

#define NB_SCAN 391            // ceil(N_NODES/256)
#define NPW1 4                 // nodes per wave, conv1 (6250 blocks)
#define NPWM 8                 // nodes per wave, conv2_heads (3125 blocks)

static_assert(N_NODES % (4 * NPW1) == 0, "conv1 grid exact");
static_assert(N_NODES % (4 * NPWM) == 0, "conv2_heads grid exact");
static_assert(N_EDGES % 256 == 0, "edge grid exact");

// ---------------- Threefry-2x32-20, key = (0, 42)  (jax.random.key(42)) ----
__device__ __forceinline__ void threefry2x32_42(uint32_t& x0, uint32_t& x1) {
    const uint32_t k0 = 0u, k1 = 42u;
    const uint32_t k2 = k0 ^ k1 ^ 0x1BD11BDAu;
    x0 += k0; x1 += k1;
#define TF_ROUND(r) { x0 += x1; x1 = (x1 << (r)) | (x1 >> (32 - (r))); x1 ^= x0; }
    TF_ROUND(13) TF_ROUND(15) TF_ROUND(26) TF_ROUND(6)
    x0 += k1; x1 += k2 + 1u;
    TF_ROUND(17) TF_ROUND(29) TF_ROUND(16) TF_ROUND(24)
    x0 += k2; x1 += k0 + 2u;
    TF_ROUND(13) TF_ROUND(15) TF_ROUND(26) TF_ROUND(6)
    x0 += k0; x1 += k1 + 3u;
    TF_ROUND(17) TF_ROUND(29) TF_ROUND(16) TF_ROUND(24)
    x0 += k1; x1 += k2 + 4u;
    TF_ROUND(13) TF_ROUND(15) TF_ROUND(26) TF_ROUND(6)
    x0 += k2; x1 += k0 + 5u;
#undef TF_ROUND
}

// XLA f32 ErfInv (Giles): matches jax.lax.erf_inv on f32
__device__ __forceinline__ float erfinv_f32(float x) {
    float w = -log1pf(-x * x);
    float p;
    if (w < 5.0f) {
        w = w - 2.5f;
        p = 2.81022636e-08f;
        p = fmaf(p, w, 3.43273939e-07f);
        p = fmaf(p, w, -3.5233877e-06f);
        p = fmaf(p, w, -4.39150654e-06f);
        p = fmaf(p, w, 0.00021858087f);
        p = fmaf(p, w, -0.00125372503f);
        p = fmaf(p, w, -0.00417768164f);
        p = fmaf(p, w, 0.246640727f);
        p = fmaf(p, w, 1.50140941f);
    } else {
        w = sqrtf(w) - 3.0f;
        p = -0.000200214257f;
        p = fmaf(p, w, 0.000100950558f);
        p = fmaf(p, w, 0.00134934322f);
        p = fmaf(p, w, -0.00367342844f);
        p = fmaf(p, w, 0.00573950773f);
        p = fmaf(p, w, -0.0076224613f);
        p = fmaf(p, w, 0.00943887047f);
        p = fmaf(p, w, 1.00167406f);
        p = fmaf(p, w, 2.83297682f);
    }
    return p * x;
}

// ---------------- CSR build: histogram of dst -------------------------------
__global__ void hist_k(const int* __restrict__ dst, int* __restrict__ deg) {
    int e = blockIdx.x * blockDim.x + threadIdx.x;
    if (e < N_EDGES) atomicAdd(&deg[dst[e]], 1);
}

// ---------------- CSR build: 3-pass exclusive scan over deg -----------------
__global__ void scan1_k(const int* __restrict__ deg, int* __restrict__ bsum) {
    __shared__ int sv[256];
    int t = threadIdx.x, i = blockIdx.x * 256 + t;
    sv[t] = (i < N_NODES) ? deg[i] : 0;
    __syncthreads();
    for (int o = 128; o > 0; o >>= 1) {
        if (t < o) sv[t] += sv[t + o];
        __syncthreads();
    }
    if (t == 0) bsum[blockIdx.x] = sv[0];
}

__global__ void scan2_k(int* __restrict__ bsum) {
    __shared__ int sv[512];
    int t = threadIdx.x;
    int v = (t < NB_SCAN) ? bsum[t] : 0;
    sv[t] = v;
    __syncthreads();
    for (int o = 1; o < 512; o <<= 1) {
        int a = (t >= o) ? sv[t - o] : 0;
        __syncthreads();
        sv[t] += a;
        __syncthreads();
    }
    if (t < NB_SCAN) bsum[t] = sv[t] - v;   // exclusive block offsets
}

__global__ void scan3_k(const int* __restrict__ deg, const int* __restrict__ bsum,
                        int* __restrict__ off, int* __restrict__ cur) {
    __shared__ int sv[256];
    int t = threadIdx.x, i = blockIdx.x * 256 + t;
    int v = (i < N_NODES) ? deg[i] : 0;
    sv[t] = v;
    __syncthreads();
    for (int o = 1; o < 256; o <<= 1) {
        int a = (t >= o) ? sv[t - o] : 0;
        __syncthreads();
        sv[t] += a;
        __syncthreads();
    }
    if (i < N_NODES) {
        int s = bsum[blockIdx.x] + sv[t] - v;
        off[i] = s;
        cur[i] = s;   // cursor; after scatter_k, cur[i] == segment end
    }
}

// ---------------- CSR build: scatter edges into dst-sorted order ------------
__global__ void scatter_k(const float* __restrict__ x, const int* __restrict__ src,
                          const int* __restrict__ dst, const float* __restrict__ ea,
                          const float* __restrict__ We1, const float* __restrict__ be1,
                          int* __restrict__ cur, int2* __restrict__ rec8,
                          float* __restrict__ m1s) {
    int e = blockIdx.x * blockDim.x + threadIdx.x;
    if (e >= N_EDGES) return;
    int s = src[e], d = dst[e];
    const float* ep = ea + (size_t)e * EAD;
    float p = be1[0];
#pragma unroll
    for (int k = 0; k < EAD; k++) p = fmaf(ep[k], We1[k], p);
    float m = x[s] + p;
    m = m > 0.0f ? m : 0.0f;
    int pos = atomicAdd(&cur[d], 1);
    rec8[pos] = make_int2(s, e);
    m1s[pos] = m;
}

// ---------------- conv1: segmented sum of m1 + fused MLP 1->64->64 ----------
__global__ void conv1_fused(const float* __restrict__ x, const float* __restrict__ m1s,
                            const int* __restrict__ off, const int* __restrict__ cur,
                            const float* __restrict__ W11, const float* __restrict__ b11,
                            const float* __restrict__ W12, const float* __restrict__ b12,
                            const float* __restrict__ eps1, float* __restrict__ hA) {
    __shared__ float sW12[H * H];
    __shared__ float stg[4][H];
    int tid = threadIdx.x;
    for (int i = tid; i < H * H; i += 256) sW12[i] = W12[i];
    int w = tid >> 6, lane = tid & 63;
    float rW11 = W11[lane], rb11 = b11[lane], rb12 = b12[lane], er = eps1[0];
    __syncthreads();
    int n0 = (blockIdx.x * 4 + w) * NPW1;
#pragma unroll
    for (int ni = 0; ni < NPW1; ni++) {
        int n = n0 + ni;
        int g0 = off[n], g1 = cur[n];
        float agg = 0.0f;
        for (int j = g0 + lane; j < g1; j += 64) agg += m1s[j];
#pragma unroll
        for (int o = 32; o > 0; o >>= 1) agg += __shfl_xor(agg, o, 64);
        float xv = x[n];
        float h1 = fmaf(er, xv, xv) + agg;
        float t = fmaf(h1, rW11, rb11);
        t = t > 0.0f ? t : 0.0f;
        stg[w][lane] = t;                  // intra-wave staging (lockstep)
        float acc = rb12;
#pragma unroll
        for (int j = 0; j < H; j++) acc = fmaf(stg[w][j], sW12[j * H + lane], acc);
        hA[(size_t)n * H + lane] = acc > 0.0f ? acc : 0.0f;
    }
}

// ---------------- conv2+heads mega-kernel -----------------------------------
// Per wave, per node: CSR windowed gather -> agg (1 f32/lane) -> fused MLP
// 64->64->64 (wave-lockstep LDS staging) -> mu/lv GEMV (lanes 0-31 mu,
// 32-63 lv) -> shfl exchange -> threefry z -> batched float4 stores to d_out
// (1KB contiguous per array per wave-batch). z also atomically accumulated
// into zsum[G][LAT] for the pool (no zws buffer, no agg/hB staging).
// The ~307us d_out write floor overlaps with gather compute of other waves.
__global__ void conv2_heads(const float* __restrict__ hA, const int2* __restrict__ rec8,
                            const float* __restrict__ ea, const int* __restrict__ batch,
                            const int* __restrict__ off, const int* __restrict__ cur,
                            const float* __restrict__ We2, const float* __restrict__ be2,
                            const float* __restrict__ W21, const float* __restrict__ b21,
                            const float* __restrict__ W22, const float* __restrict__ b22,
                            const float* __restrict__ eps2,
                            const float* __restrict__ Wmu, const float* __restrict__ bmu,
                            const float* __restrict__ Wlv, const float* __restrict__ blv,
                            float4* __restrict__ out4, float* __restrict__ zsum) {
    __shared__ float sW21[H * H], sW22[H * H];
    __shared__ float sWm[H * LAT], sWl[H * LAT];
    __shared__ float4 srec[4][64][2];
    __shared__ float stg[4][H];
    __shared__ float4 szout[4][3][NPWM][LAT / 4];
    int tid = threadIdx.x;
    for (int i = tid; i < H * H; i += 256) { sW21[i] = W21[i]; sW22[i] = W22[i]; }
    for (int i = tid; i < H * LAT; i += 256) { sWm[i] = Wmu[i]; sWl[i] = Wlv[i]; }
    int w = tid >> 6, lane = tid & 63;
    float rW[EAD];
#pragma unroll
    for (int k = 0; k < EAD; k++) rW[k] = We2[k * H + lane];
    float rbe2 = be2[lane], rb21 = b21[lane], rb22 = b22[lane], er = eps2[0];
    int l = lane & 31;
    float rbh = (lane < LAT) ? bmu[l] : blv[l];
    __syncthreads();

    int n0 = (blockIdx.x * 4 + w) * NPWM;
    int eend = cur[n0 + NPWM - 1];
    int sbase = -(1 << 30);

    auto restage = [&](int g) {
        sbase = g;
        int cnt = eend - g; cnt = cnt > 64 ? 64 : cnt;
        float a0 = 0, a1 = 0, a2 = 0, a3 = 0, a4 = 0, a5 = 0, a6 = 0;
        int s = 0;
        if (lane < cnt) {
            int2 r = rec8[g + lane];
            s = r.x;
            const float* ep = ea + (size_t)r.y * EAD;
            a0 = ep[0]; a1 = ep[1]; a2 = ep[2]; a3 = ep[3];
            a4 = ep[4]; a5 = ep[5]; a6 = ep[6];
        }
        srec[w][lane][0] = make_float4(a0, a1, a2, a3);
        srec[w][lane][1] = make_float4(a4, a5, a6, __int_as_float(s));
    };

    for (int ni = 0; ni < NPWM; ni++) {
        int n = n0 + ni;
        int g = off[n], gend = cur[n];
        float acc = 0.0f;
        while (g + 4 <= gend) {
            if (g + 4 > sbase + 64) restage(g);
            int b = g - sbase;
            float4 A0 = srec[w][b + 0][0], B0 = srec[w][b + 0][1];
            float4 A1 = srec[w][b + 1][0], B1 = srec[w][b + 1][1];
            float4 A2 = srec[w][b + 2][0], B2 = srec[w][b + 2][1];
            float4 A3 = srec[w][b + 3][0], B3 = srec[w][b + 3][1];
            int s0 = __builtin_amdgcn_readfirstlane(__float_as_int(B0.w));
            int s1 = __builtin_amdgcn_readfirstlane(__float_as_int(B1.w));
            int s2 = __builtin_amdgcn_readfirstlane(__float_as_int(B2.w));
            int s3 = __builtin_amdgcn_readfirstlane(__float_as_int(B3.w));
            float hv0 = hA[(size_t)s0 * H + lane];
            float hv1 = hA[(size_t)s1 * H + lane];
            float hv2 = hA[(size_t)s2 * H + lane];
            float hv3 = hA[(size_t)s3 * H + lane];
            float p0 = rbe2, p1 = rbe2, p2 = rbe2, p3 = rbe2;
            p0 = fmaf(A0.x, rW[0], p0); p0 = fmaf(A0.y, rW[1], p0);
            p0 = fmaf(A0.z, rW[2], p0); p0 = fmaf(A0.w, rW[3], p0);
            p0 = fmaf(B0.x, rW[4], p0); p0 = fmaf(B0.y, rW[5], p0);
            p0 = fmaf(B0.z, rW[6], p0);
            p1 = fmaf(A1.x, rW[0], p1); p1 = fmaf(A1.y, rW[1], p1);
            p1 = fmaf(A1.z, rW[2], p1); p1 = fmaf(A1.w, rW[3], p1);
            p1 = fmaf(B1.x, rW[4], p1); p1 = fmaf(B1.y, rW[5], p1);
            p1 = fmaf(B1.z, rW[6], p1);
            p2 = fmaf(A2.x, rW[0], p2); p2 = fmaf(A2.y, rW[1], p2);
            p2 = fmaf(A2.z, rW[2], p2); p2 = fmaf(A2.w, rW[3], p2);
            p2 = fmaf(B2.x, rW[4], p2); p2 = fmaf(B2.y, rW[5], p2);
            p2 = fmaf(B2.z, rW[6], p2);
            p3 = fmaf(A3.x, rW[0], p3); p3 = fmaf(A3.y, rW[1], p3);
            p3 = fmaf(A3.z, rW[2], p3); p3 = fmaf(A3.w, rW[3], p3);
            p3 = fmaf(B3.x, rW[4], p3); p3 = fmaf(B3.y, rW[5], p3);
            p3 = fmaf(B3.z, rW[6], p3);
            acc += fmaxf(hv0 + p0, 0.0f);
            acc += fmaxf(hv1 + p1, 0.0f);
            acc += fmaxf(hv2 + p2, 0.0f);
            acc += fmaxf(hv3 + p3, 0.0f);
            g += 4;
        }
        while (g < gend) {
            if (g >= sbase + 64) restage(g);
            int b = g - sbase;
            float4 A = srec[w][b][0], B = srec[w][b][1];
            int s = __builtin_amdgcn_readfirstlane(__float_as_int(B.w));
            float hv = hA[(size_t)s * H + lane];
            float p = rbe2;
            p = fmaf(A.x, rW[0], p); p = fmaf(A.y, rW[1], p);
            p = fmaf(A.z, rW[2], p); p = fmaf(A.w, rW[3], p);
            p = fmaf(B.x, rW[4], p); p = fmaf(B.y, rW[5], p);
            p = fmaf(B.z, rW[6], p);
            acc += fmaxf(hv + p, 0.0f);
            g++;
        }
        // fused 2-layer MLP (wave-synchronous LDS staging, r1-proven pattern)
        float hself = hA[(size_t)n * H + lane];
        float h2 = fmaf(er, hself, hself) + acc;
        stg[w][lane] = h2;
        float t = rb21;
#pragma unroll
        for (int j = 0; j < H; j++) t = fmaf(stg[w][j], sW21[j * H + lane], t);
        t = t > 0.0f ? t : 0.0f;
        stg[w][lane] = t;
        float o2 = rb22;
#pragma unroll
        for (int j = 0; j < H; j++) o2 = fmaf(stg[w][j], sW22[j * H + lane], o2);
        o2 = o2 > 0.0f ? o2 : 0.0f;
        stg[w][lane] = o2;                 // hB row, lane = feature
        // heads GEMV: lanes 0-31 compute mu[l], lanes 32-63 compute lv[l]
        const float* Wh = (lane < LAT) ? sWm : sWl;
        float v = rbh;
#pragma unroll
        for (int j = 0; j < H; j++) v = fmaf(stg[w][j], Wh[j * LAT + l], v);
        float o = __shfl(v, lane ^ 32);    // low: o=lv ; high: o=mu
        if (lane < LAT) {
            float muv = v, lvv = o;
            int i = n * LAT + l;
            uint32_t x0 = 0u, x1 = (uint32_t)i;
            threefry2x32_42(x0, x1);
            uint32_t bits = x0 ^ x1;
            float f = __uint_as_float((bits >> 9) | 0x3F800000u) - 1.0f;
            const float lo = -0.99999994f;
            float u = fmaxf(lo, fmaf(f, 2.0f, lo));
            float noise = 1.41421356237309515f * erfinv_f32(u);
            float z = fmaf(noise, expf(0.5f * lvv), muv);
            float* zp = (float*)&szout[w][0][ni][0];
            float* mp = (float*)&szout[w][1][ni][0];
            float* lp = (float*)&szout[w][2][ni][0];
            zp[l] = z; mp[l] = muv; lp[l] = lvv;
            int bg = batch[n];
            atomicAdd(&zsum[bg * LAT + l], z);
        }
    }
    // batched wave-synchronous float4 stores: 1KB contiguous per array
    int nl = lane >> 3, f4 = lane & 7;
#pragma unroll
    for (int it = 0; it < 3; it++)
        out4[(size_t)it * (NZ / 4) + (size_t)(n0 + nl) * 8 + f4] = szout[w][it][nl][f4];
}

// ---------------- pool + logits from zsum; batch SORTED ---------------------
__global__ void pool2_k(const float* __restrict__ zsum, const int* __restrict__ batch,
                        const float* __restrict__ Wc, const float* __restrict__ bc,
                        float* __restrict__ out) {
    __shared__ float emb[LAT];
    int g = blockIdx.x, tid = threadIdx.x;
    int lo = 0, hi = N_NODES;
    while (lo < hi) { int mid = (lo + hi) >> 1; if (batch[mid] < g) lo = mid + 1; else hi = mid; }
    int start = lo;
    hi = N_NODES;
    while (lo < hi) { int mid = (lo + hi) >> 1; if (batch[mid] < g + 1) lo = mid + 1; else hi = mid; }
    int end = lo;
    if (tid < LAT) {
        float invc = 1.0f / fmaxf((float)(end - start), 1.0f);
        emb[tid] = zsum[g * LAT + tid] * invc;
    }
    __syncthreads();
    if (tid < NC) {
        float r = bc[tid];
#pragma unroll
        for (int l = 0; l < LAT; l++) r = fmaf(emb[l], Wc[l * NC + tid], r);
        out[g * NC + tid] = r;
    }
}

extern "C" void kernel_launch(void* const* d_in, const int* in_sizes, int n_in,
                              void* d_out, int out_size, void* d_ws, size_t ws_size,
                              hipStream_t stream) {
    const float* x     = (const float*)d_in[0];
    const int*   ei    = (const int*)d_in[1];
    const float* ea    = (const float*)d_in[2];
    const int*   batch = (const int*)d_in[3];
    const float* We1   = (const float*)d_in[4];
    const float* be1   = (const float*)d_in[5];
    const float* W11   = (const float*)d_in[6];
    const float* b11   = (const float*)d_in[7];
    const float* W12   = (const float*)d_in[8];
    const float* b12   = (const float*)d_in[9];
    const float* eps1  = (const float*)d_in[10];
    const float* We2   = (const float*)d_in[11];
    const float* be2   = (const float*)d_in[12];
    const float* W21   = (const float*)d_in[13];
    const float* b21   = (const float*)d_in[14];
    const float* W22   = (const float*)d_in[15];
    const float* b22   = (const float*)d_in[16];
    const float* eps2  = (const float*)d_in[17];
    const float* Wmu   = (const float*)d_in[18];
    const float* bmu   = (const float*)d_in[19];
    const float* Wlv   = (const float*)d_in[20];
    const float* blv   = (const float*)d_in[21];
    const float* Wc    = (const float*)d_in[22];
    const float* bc    = (const float*)d_in[23];

    // ws layout (46.07 MB, inside the proven 51.6 MB budget):
    //   [zsum G*LAT]                          0.065 MB (zeroed each launch)
    //   [deg N][off N][cur N][bsum 512]       1.20 MB
    //   [rec8 E int2]                        12.80 MB
    //   [m1s E float]                         6.40 MB
    //   [hA  N*H float]                      25.60 MB
    // No agg/hB/zws staging buffers; d_out receives only the final
    // z/mu/lv float4 batches + logits.
    float* zsum = (float*)d_ws;
    int*   deg  = (int*)d_ws + NG * LAT;
    int*   off  = deg + N_NODES;
    int*   cur  = off + N_NODES;
    int*   bsum = cur + N_NODES;
    int2*  rec8 = (int2*)(bsum + 512);
    float* m1s  = (float*)(rec8 + N_EDGES);
    float* hA   = m1s + N_EDGES;
    float* outf = (float*)d_out;

    // zero zsum + deg (contiguous)
    hipMemsetAsync(d_ws, 0, (size_t)(NG * LAT + N_NODES) * sizeof(float), stream);

    const int* src = ei;
    const int* dst = ei + N_EDGES;

    hist_k<<<N_EDGES / 256, 256, 0, stream>>>(dst, deg);
    scan1_k<<<NB_SCAN, 256, 0, stream>>>(deg, bsum);
    scan2_k<<<1, 512, 0, stream>>>(bsum);
    scan3_k<<<NB_SCAN, 256, 0, stream>>>(deg, bsum, off, cur);
    scatter_k<<<N_EDGES / 256, 256, 0, stream>>>(x, src, dst, ea, We1, be1, cur, rec8, m1s);
    conv1_fused<<<N_NODES / (4 * NPW1), 256, 0, stream>>>(
        x, m1s, off, cur, W11, b11, W12, b12, eps1, hA);
    conv2_heads<<<N_NODES / (4 * NPWM), 256, 0, stream>>>(
        hA, rec8, ea, batch, off, cur, We2, be2, W21, b21, W22, b22, eps2,
        Wmu, bmu, Wlv, blv, (float4*)outf, zsum);
    pool2_k<<<NG, 64, 0, stream>>>(zsum, batch, Wc, bc, outf + 3 * (size_t)NZ);
}